// Round 2
// baseline (1642.247 us; speedup 1.0000x reference)
//
#include <hip/hip_runtime.h>
#include <math.h>

#define RMAX 4.0f

__device__ __forceinline__ float tanh_fast(float x){
  float e = __expf(2.0f * x);
  return 1.0f - 2.0f / (e + 1.0f);
}
__device__ __forceinline__ float normact(float s){
  float ns = fabsf(s);
  return s * tanh_fast(ns) / (ns + 1e-8f);
}

// ---------------- precompute per-species tables ----------------
// x1tab[c][j] = sum_i (Wna[c][i]/2) * Wlin1[i][j] / sqrt(32)        [4x32]
// sctab[c][k] = sum_i (Wna[c][i]/2) * Wsc[i][c][k] / sqrt(128)      [4x64]
__global__ void k_pre(const float* __restrict__ Wna, const float* __restrict__ Wlin1,
                      const float* __restrict__ Wsc,
                      float* __restrict__ x1tab, float* __restrict__ sctab){
  int id = threadIdx.x;
  if (id < 128){
    int c = id >> 5, j = id & 31;
    float acc = 0.f;
    for (int i = 0; i < 32; ++i) acc += Wna[c*32+i] * Wlin1[i*32+j];
    x1tab[id] = acc * (0.5f * 0.17677669529663687f);
  }
  if (id < 256){
    int c = id >> 6, k = id & 63;
    float acc = 0.f;
    for (int i = 0; i < 32; ++i) acc += Wna[c*32+i] * Wsc[(i*4+c)*64+k];
    sctab[id] = acc * (0.5f * 0.08838834764831843f);
  }
}

// ---------------- edge compaction (drop r >= RMAX) ----------------
__global__ void k_compact(const float* __restrict__ coords, const int* __restrict__ ei,
                          const int* __restrict__ species, int E, int* __restrict__ cnt,
                          int* __restrict__ cpk, float* __restrict__ crr){
  int i = blockIdx.x * blockDim.x + threadIdx.x;
  bool alive = false; int pk = 0; float r = 0.f;
  if (i < E){
    int s = ei[i], d = ei[E + i];
    float dx = coords[3*d+0] - coords[3*s+0];
    float dy = coords[3*d+1] - coords[3*s+1];
    float dz = coords[3*d+2] - coords[3*s+2];
    r = sqrtf(dx*dx + dy*dy + dz*dz + 1e-8f);
    if (r < RMAX){ alive = true; pk = d | (species[s] << 27); }
  }
  unsigned long long m = __ballot(alive);
  if (m == 0ull) return;
  int lane = threadIdx.x & 63;
  int leader = __ffsll((long long)m) - 1;
  int base = 0;
  if (lane == leader) base = atomicAdd(cnt, __popcll(m));
  base = __shfl(base, leader, 64);
  if (alive){
    int pos = base + __popcll(m & ((1ull << lane) - 1ull));
    cpk[pos] = pk; crr[pos] = r;
  }
}

// ---------------- per-edge radial MLP + scatter ----------------
// ea[8] -> tanh(ea@Wr1/sqrt8) -> tanh(h@Wr2/8) -> w = h@Wr3[:, :32]/8
// msg = w * x1tab[class(src)]; atomicAdd into agg[dst][0:32]
__global__ void __launch_bounds__(256) k_edge(
    const int* __restrict__ cpk, const float* __restrict__ crr,
    const int* __restrict__ cnt,
    const float* __restrict__ Wr1, const float* __restrict__ Wr2,
    const float* __restrict__ Wr3, const float* __restrict__ x1tab,
    float* __restrict__ agg){
  __shared__ float sW1[8*64];    // scaled 1/sqrt(8)
  __shared__ float sW2T[64*64];  // transposed, scaled 1/8
  __shared__ float sW3[64*32];   // cols 0..31 of Wr3, scaled 1/8
  __shared__ float sX1[4*32];
  int n = *cnt;
  if ((int)(blockIdx.x * blockDim.x) >= n) return;
  int t = threadIdx.x;
  for (int i = t; i < 512; i += 256) sW1[i] = Wr1[i] * 0.3535533905932738f;
  for (int i = t; i < 4096; i += 256){ int rr = i >> 6, cc = i & 63; sW2T[cc*64+rr] = Wr2[i] * 0.125f; }
  for (int i = t; i < 2048; i += 256){ int rr = i >> 5, cc = i & 31; sW3[i] = Wr3[rr*64+cc] * 0.125f; }
  for (int i = t; i < 128; i += 256) sX1[i] = x1tab[i];
  __syncthreads();
  int i = blockIdx.x * blockDim.x + t;
  if (i >= n) return;

  float r = crr[i];
  int pk = cpk[i];
  // edge_attr = bessel * fcut  (r < RMAX guaranteed)
  float u = r * 0.25f;
  float u2 = u*u, u4 = u2*u2, u6 = u4*u2;
  float fc = 1.0f + u6 * (-28.0f + u * (48.0f - 21.0f * u));
  float pref = 0.5f / r * fc;
  float ea[8];
  #pragma unroll
  for (int k = 1; k <= 8; ++k) ea[k-1] = __sinf(0.78539816339744831f * r * (float)k) * pref;

  // layer 1: 8 -> 64
  float h1[64];
  #pragma unroll
  for (int j = 0; j < 64; j += 4){
    float ax = 0.f, ay = 0.f, az = 0.f, aw = 0.f;
    #pragma unroll
    for (int k = 0; k < 8; ++k){
      const float4 w4 = *(const float4*)&sW1[k*64 + j];
      ax += ea[k]*w4.x; ay += ea[k]*w4.y; az += ea[k]*w4.z; aw += ea[k]*w4.w;
    }
    h1[j]   = tanh_fast(ax); h1[j+1] = tanh_fast(ay);
    h1[j+2] = tanh_fast(az); h1[j+3] = tanh_fast(aw);
  }

  // layer 2 (64->64, tanh) fused with layer 3 (64->32)
  float wsx[8], wsy[8], wsz[8], wsw[8];
  #pragma unroll
  for (int g = 0; g < 8; ++g){ wsx[g]=0.f; wsy[g]=0.f; wsz[g]=0.f; wsw[g]=0.f; }
  for (int j = 0; j < 64; ++j){
    float ax = 0.f, ay = 0.f, az = 0.f, aw = 0.f;
    #pragma unroll
    for (int k = 0; k < 64; k += 4){
      const float4 w4 = *(const float4*)&sW2T[j*64 + k];
      ax += h1[k]*w4.x; ay += h1[k+1]*w4.y; az += h1[k+2]*w4.z; aw += h1[k+3]*w4.w;
    }
    float tj = tanh_fast(ax + ay + az + aw);
    #pragma unroll
    for (int g = 0; g < 8; ++g){
      const float4 w4 = *(const float4*)&sW3[j*32 + g*4];
      wsx[g] += tj*w4.x; wsy[g] += tj*w4.y; wsz[g] += tj*w4.z; wsw[g] += tj*w4.w;
    }
  }

  int d = pk & 0x07FFFFFF;
  int c = pk >> 27;
  float* ag = agg + (size_t)d * 32;
  const float* xr = &sX1[c*32];
  #pragma unroll
  for (int g = 0; g < 8; ++g){
    const float4 xv = *(const float4*)&xr[g*4];
    atomicAdd(ag + g*4 + 0, wsx[g]*xv.x);
    atomicAdd(ag + g*4 + 1, wsy[g]*xv.y);
    atomicAdd(ag + g*4 + 2, wsz[g]*xv.z);
    atomicAdd(ag + g*4 + 3, wsw[g]*xv.w);
  }
}

// ---------------- generic node-tail layer: out = act(in@W*scale [+sc]) [+resid] ----
// ACT: 1 = normact, 2 = tanh. MO/4 threads per row, float4 output per thread.
template<int K, int MO, int ACT, bool HAS_SC, bool HAS_RES>
__global__ void k_lin(const float* __restrict__ in, const float* __restrict__ W,
                      float scale, const float* __restrict__ sctab,
                      const int* __restrict__ species,
                      const float* __restrict__ resid,
                      float* __restrict__ out, int N){
  constexpr int TPR = MO / 4;
  int gid = blockIdx.x * blockDim.x + threadIdx.x;
  int nidx = gid / TPR;
  int k4 = (gid % TPR) * 4;
  if (nidx >= N) return;
  const float* inr = in + (size_t)nidx * K;
  float ax = 0.f, ay = 0.f, az = 0.f, aw = 0.f;
  for (int j = 0; j < K; ++j){
    float aj = inr[j];
    const float4 w4 = *(const float4*)&W[j*MO + k4];
    ax += aj*w4.x; ay += aj*w4.y; az += aj*w4.z; aw += aj*w4.w;
  }
  ax *= scale; ay *= scale; az *= scale; aw *= scale;
  if (HAS_SC){
    int c = species[nidx];
    const float4 b4 = *(const float4*)&sctab[c*MO + k4];
    ax += b4.x; ay += b4.y; az += b4.z; aw += b4.w;
  }
  if (ACT == 1){ ax = normact(ax); ay = normact(ay); az = normact(az); aw = normact(aw); }
  else        { ax = tanh_fast(ax); ay = tanh_fast(ay); az = tanh_fast(az); aw = tanh_fast(aw); }
  if (HAS_RES){
    const float4 r4 = *(const float4*)&resid[(size_t)nidx*MO + k4];
    ax += r4.x; ay += r4.y; az += r4.z; aw += r4.w;
  }
  float4 o4 = make_float4(ax, ay, az, aw);
  *(float4*)&out[(size_t)nidx*MO + k4] = o4;
}

__global__ void k_fin(const float* __restrict__ g, const float* __restrict__ Wm3,
                      float* __restrict__ out, int N){
  int nidx = blockIdx.x * blockDim.x + threadIdx.x;
  if (nidx >= N) return;
  const float* gr = g + (size_t)nidx * 32;
  float acc = 0.f;
  #pragma unroll
  for (int j = 0; j < 32; ++j) acc += gr[j] * Wm3[j];
  out[nidx] = acc * 0.17677669529663687f;
}

extern "C" void kernel_launch(void* const* d_in, const int* in_sizes, int n_in,
                              void* d_out, int out_size, void* d_ws, size_t ws_size,
                              hipStream_t stream) {
  const float* coords   = (const float*)d_in[0];
  const int*   species  = (const int*)  d_in[1];
  const int*   ei       = (const int*)  d_in[2];
  const float* Wna      = (const float*)d_in[4];
  const float* Wlin1    = (const float*)d_in[5];
  const float* Wr1      = (const float*)d_in[6];
  const float* Wr2      = (const float*)d_in[7];
  const float* Wr3      = (const float*)d_in[8];
  const float* W2s      = (const float*)d_in[9];
  const float* Wsc      = (const float*)d_in[11];
  const float* Wfin     = (const float*)d_in[12];
  const float* Wr       = (const float*)d_in[13];
  const float* Wm1      = (const float*)d_in[14];
  const float* Wm2      = (const float*)d_in[15];
  const float* Wm3      = (const float*)d_in[16];
  float* out = (float*)d_out;

  const int N = in_sizes[1];
  const int E = in_sizes[2] / 2;

  char* ws = (char*)d_ws;
  size_t offA   = 0;                               // agg [N*32] f32 ; later y ; later g
  size_t offX1  = offA  + (size_t)N*32*4;          // x1tab 512B
  size_t offSC  = offX1 + 512;                     // sctab 1024B
  size_t offCNT = offSC + 1024;                    // cnt (16B pad)
  size_t offPK  = offCNT + 16;                     // cpk [E] ; later y2
  size_t offRR  = offPK + (size_t)E*4;             // crr [E]
  size_t offS   = offRR + (size_t)E*4;             // S [N*64] f32 ; later h
  // total = offS + N*64*4  (~51.2 MB for N=100K, E=1.6M)

  float* agg   = (float*)(ws + offA);
  float* x1tab = (float*)(ws + offX1);
  float* sctab = (float*)(ws + offSC);
  int*   cnt   = (int*)  (ws + offCNT);
  int*   cpk   = (int*)  (ws + offPK);
  float* crr   = (float*)(ws + offRR);
  float* Sbuf  = (float*)(ws + offS);
  float* ybuf  = (float*)(ws + offA);    // alias agg (dead after K1)
  float* y2buf = (float*)(ws + offPK);   // alias cpk/crr (dead after k_edge)
  float* hbuf  = (float*)(ws + offS);    // alias S (dead after K2)
  float* gbuf  = (float*)(ws + offA);    // alias y (dead after K3)

  hipMemsetAsync(agg, 0, (size_t)N*32*4, stream);
  hipMemsetAsync(cnt, 0, 16, stream);

  k_pre<<<1, 256, 0, stream>>>(Wna, Wlin1, Wsc, x1tab, sctab);

  int blkE = (E + 255) / 256;
  k_compact<<<blkE, 256, 0, stream>>>(coords, ei, species, E, cnt, cpk, crr);
  k_edge<<<blkE, 256, 0, stream>>>(cpk, crr, cnt, Wr1, Wr2, Wr3, x1tab, agg);

  const float s_16s32 = 0.0625f * 0.17677669529663687f;  // 1/16 * 1/sqrt(32)
  const float s_s64   = 0.125f;                           // 1/sqrt(64)
  const float s_s32   = 0.17677669529663687f;             // 1/sqrt(32)

  int blk16 = ((size_t)N*16 + 255) / 256;
  int blk8  = ((size_t)N*8  + 255) / 256;
  // K1: s = normact(agg @ W2s * s_16s32 + sctab[species])
  k_lin<32,64,1,true ,false><<<blk16,256,0,stream>>>(agg,  W2s,  s_16s32, sctab, species, nullptr, Sbuf,  N);
  // K2: y = normact(S @ Wfin * s_s64)
  k_lin<64,32,1,false,false><<<blk8 ,256,0,stream>>>(Sbuf, Wfin, s_s64,   nullptr, nullptr, nullptr, ybuf, N);
  // K3: y2 = y + normact(y @ Wr * s_s32)
  k_lin<32,32,1,false,true ><<<blk8 ,256,0,stream>>>(ybuf, Wr,   s_s32,   nullptr, nullptr, ybuf,   y2buf, N);
  // K4: h = tanh(y2 @ Wm1 * s_s32)
  k_lin<32,64,2,false,false><<<blk16,256,0,stream>>>(y2buf,Wm1,  s_s32,   nullptr, nullptr, nullptr, hbuf, N);
  // K5: g = tanh(h @ Wm2 * s_s64)
  k_lin<64,32,2,false,false><<<blk8 ,256,0,stream>>>(hbuf, Wm2,  s_s64,   nullptr, nullptr, nullptr, gbuf, N);
  // K6: out = g @ Wm3 * s_s32
  k_fin<<<(N + 255) / 256, 256, 0, stream>>>(gbuf, Wm3, out, N);
}

// Round 3
// 1463.755 us; speedup vs baseline: 1.1219x; 1.1219x over previous
//
#include <hip/hip_runtime.h>
#include <math.h>

#define RMAX 4.0f
#define NTAB 4096   // intervals over [0,4); rows 0..4096 built (+pad)

__device__ __forceinline__ float tanh_fast(float x){
  float e = __expf(2.0f * x);
  return 1.0f - 2.0f / (e + 1.0f);
}
__device__ __forceinline__ float normact(float s){
  float ns = fabsf(s);
  return s * tanh_fast(ns) / (ns + 1e-8f);
}

// ---------------- precompute per-species tables ----------------
// x1tab[c][j] = sum_i (Wna[c][i]/2) * Wlin1[i][j] / sqrt(32)        [4x32]
// sctab[c][k] = sum_i (Wna[c][i]/2) * Wsc[i][c][k] / sqrt(128)      [4x64]
__global__ void k_pre(const float* __restrict__ Wna, const float* __restrict__ Wlin1,
                      const float* __restrict__ Wsc,
                      float* __restrict__ x1tab, float* __restrict__ sctab){
  int id = threadIdx.x;
  if (id < 128){
    int c = id >> 5, j = id & 31;
    float acc = 0.f;
    for (int i = 0; i < 32; ++i) acc += Wna[c*32+i] * Wlin1[i*32+j];
    x1tab[id] = acc * (0.5f * 0.17677669529663687f);
  }
  if (id < 256){
    int c = id >> 6, k = id & 63;
    float acc = 0.f;
    for (int i = 0; i < 32; ++i) acc += Wna[c*32+i] * Wsc[(i*4+c)*64+k];
    sctab[id] = acc * (0.5f * 0.08838834764831843f);
  }
}

// ---------------- build radial table: tab[(i*4+c)*32+g] = w(r_i)[g]*x1tab[c][g] ----
__global__ void __launch_bounds__(256) k_tab(
    const float* __restrict__ Wr1, const float* __restrict__ Wr2,
    const float* __restrict__ Wr3, const float* __restrict__ x1tab,
    float* __restrict__ tab){
  __shared__ float sW1[8*64];    // scaled 1/sqrt(8)
  __shared__ float sW2T[64*64];  // transposed, scaled 1/8
  __shared__ float sW3[64*32];   // cols 0..31 of Wr3, scaled 1/8
  __shared__ float sX1[4*32];
  int t = threadIdx.x;
  for (int i = t; i < 512; i += 256) sW1[i] = Wr1[i] * 0.3535533905932738f;
  for (int i = t; i < 4096; i += 256){ int rr = i >> 6, cc = i & 63; sW2T[cc*64+rr] = Wr2[i] * 0.125f; }
  for (int i = t; i < 2048; i += 256){ int rr = i >> 5, cc = i & 31; sW3[i] = Wr3[rr*64+cc] * 0.125f; }
  for (int i = t; i < 128; i += 256) sX1[i] = x1tab[i];
  __syncthreads();
  int i = blockIdx.x * 256 + t;
  if (i > NTAB) return;
  float r = fmaxf((float)i * (RMAX / (float)NTAB), 1e-6f);

  float u = r * 0.25f;
  float u2 = u*u, u4 = u2*u2, u6 = u4*u2;
  float fc = 1.0f + u6 * (-28.0f + u * (48.0f - 21.0f * u));
  float pref = 0.5f / r * fc;
  float ea[8];
  #pragma unroll
  for (int k = 1; k <= 8; ++k) ea[k-1] = __sinf(0.78539816339744831f * r * (float)k) * pref;

  float h1[64];
  #pragma unroll
  for (int j = 0; j < 64; j += 4){
    float ax = 0.f, ay = 0.f, az = 0.f, aw = 0.f;
    #pragma unroll
    for (int k = 0; k < 8; ++k){
      const float4 w4 = *(const float4*)&sW1[k*64 + j];
      ax += ea[k]*w4.x; ay += ea[k]*w4.y; az += ea[k]*w4.z; aw += ea[k]*w4.w;
    }
    h1[j]   = tanh_fast(ax); h1[j+1] = tanh_fast(ay);
    h1[j+2] = tanh_fast(az); h1[j+3] = tanh_fast(aw);
  }

  float wsx[8], wsy[8], wsz[8], wsw[8];
  #pragma unroll
  for (int g = 0; g < 8; ++g){ wsx[g]=0.f; wsy[g]=0.f; wsz[g]=0.f; wsw[g]=0.f; }
  for (int j = 0; j < 64; ++j){
    float ax = 0.f, ay = 0.f, az = 0.f, aw = 0.f;
    #pragma unroll
    for (int k = 0; k < 64; k += 4){
      const float4 w4 = *(const float4*)&sW2T[j*64 + k];
      ax += h1[k]*w4.x; ay += h1[k+1]*w4.y; az += h1[k+2]*w4.z; aw += h1[k+3]*w4.w;
    }
    float tj = tanh_fast(ax + ay + az + aw);
    #pragma unroll
    for (int g = 0; g < 8; ++g){
      const float4 w4 = *(const float4*)&sW3[j*32 + g*4];
      wsx[g] += tj*w4.x; wsy[g] += tj*w4.y; wsz[g] += tj*w4.z; wsw[g] += tj*w4.w;
    }
  }

  #pragma unroll
  for (int c = 0; c < 4; ++c){
    float* row = tab + ((size_t)i*4 + c)*32;
    #pragma unroll
    for (int g = 0; g < 8; ++g){
      const float4 xv = *(const float4*)&sX1[c*32 + g*4];
      row[g*4+0] = wsx[g]*xv.x;
      row[g*4+1] = wsy[g]*xv.y;
      row[g*4+2] = wsz[g]*xv.z;
      row[g*4+3] = wsw[g]*xv.w;
    }
  }
}

// ---------------- fused edge kernel: r -> table lerp -> atomic scatter ----------
__global__ void __launch_bounds__(256) k_edge2(
    const float* __restrict__ coords, const int* __restrict__ ei,
    const int* __restrict__ species, const float* __restrict__ tab,
    float* __restrict__ agg, int E){
  int i = blockIdx.x * blockDim.x + threadIdx.x;
  if (i >= E) return;
  int s = ei[i], d = ei[E + i];
  float3 cs = *(const float3*)(coords + 3*s);
  float3 cd = *(const float3*)(coords + 3*d);
  float dx = cd.x - cs.x, dy = cd.y - cs.y, dz = cd.z - cs.z;
  float r2 = dx*dx + dy*dy + dz*dz + 1e-8f;
  if (r2 >= RMAX*RMAX) return;           // fcut=0 -> msg exactly 0
  float r = sqrtf(r2);
  int c = species[s];
  float tt = r * ((float)NTAB / RMAX);
  int i0 = (int)tt;
  i0 = min(i0, NTAB - 1);
  float f = tt - (float)i0;
  const float4* r0 = (const float4*)(tab + ((size_t)i0*4 + c)*32);
  const float4* r1 = r0 + 32;            // next r row: +4*32 floats = 32 float4
  float* ag = agg + (size_t)d * 32;
  #pragma unroll
  for (int g = 0; g < 8; ++g){
    float4 a = r0[g], b = r1[g];
    atomicAdd(ag + g*4 + 0, a.x + f*(b.x - a.x));
    atomicAdd(ag + g*4 + 1, a.y + f*(b.y - a.y));
    atomicAdd(ag + g*4 + 2, a.z + f*(b.z - a.z));
    atomicAdd(ag + g*4 + 3, a.w + f*(b.w - a.w));
  }
}

// ---------------- fully fused node tail: agg row -> out, one thread per node ----
__global__ void __launch_bounds__(256) k_node(
    const float* __restrict__ agg, const float* __restrict__ sctab,
    const int* __restrict__ species,
    const float* __restrict__ W2s, const float* __restrict__ Wfin,
    const float* __restrict__ Wr,  const float* __restrict__ Wm1,
    const float* __restrict__ Wm2, const float* __restrict__ Wm3,
    float* __restrict__ out, int N){
  const float s_16s32 = 0.0625f * 0.17677669529663687f;
  const float s_s64   = 0.125f;
  const float s_s32   = 0.17677669529663687f;
  int n = blockIdx.x * 256 + threadIdx.x;
  if (n >= N) return;
  int c = species[n];
  float a[32];
  {
    const float* ar = agg + (size_t)n*32;
    #pragma unroll
    for (int j = 0; j < 32; j += 4){
      float4 v = *(const float4*)&ar[j];
      a[j]=v.x; a[j+1]=v.y; a[j+2]=v.z; a[j+3]=v.w;
    }
  }
  // S[64] = normact(a @ W2s * s + sctab[c])
  float S[64];
  #pragma unroll
  for (int k = 0; k < 64; k += 4){
    float ax=0.f, ay=0.f, az=0.f, aw=0.f;
    #pragma unroll
    for (int j = 0; j < 32; ++j){
      const float4 w4 = *(const float4*)&W2s[j*64 + k];
      ax += a[j]*w4.x; ay += a[j]*w4.y; az += a[j]*w4.z; aw += a[j]*w4.w;
    }
    const float4 b4 = *(const float4*)&sctab[c*64 + k];
    S[k]   = normact(ax*s_16s32 + b4.x);
    S[k+1] = normact(ay*s_16s32 + b4.y);
    S[k+2] = normact(az*s_16s32 + b4.z);
    S[k+3] = normact(aw*s_16s32 + b4.w);
  }
  // y[32] = normact(S @ Wfin * s_s64)  (reuse a)
  #pragma unroll
  for (int k = 0; k < 32; k += 4){
    float ax=0.f, ay=0.f, az=0.f, aw=0.f;
    #pragma unroll
    for (int j = 0; j < 64; ++j){
      const float4 w4 = *(const float4*)&Wfin[j*32 + k];
      ax += S[j]*w4.x; ay += S[j]*w4.y; az += S[j]*w4.z; aw += S[j]*w4.w;
    }
    a[k]   = normact(ax*s_s64);
    a[k+1] = normact(ay*s_s64);
    a[k+2] = normact(az*s_s64);
    a[k+3] = normact(aw*s_s64);
  }
  // y2[32] = y + normact(y @ Wr * s_s32)
  float y2[32];
  #pragma unroll
  for (int k = 0; k < 32; k += 4){
    float ax=0.f, ay=0.f, az=0.f, aw=0.f;
    #pragma unroll
    for (int j = 0; j < 32; ++j){
      const float4 w4 = *(const float4*)&Wr[j*32 + k];
      ax += a[j]*w4.x; ay += a[j]*w4.y; az += a[j]*w4.z; aw += a[j]*w4.w;
    }
    y2[k]   = a[k]   + normact(ax*s_s32);
    y2[k+1] = a[k+1] + normact(ay*s_s32);
    y2[k+2] = a[k+2] + normact(az*s_s32);
    y2[k+3] = a[k+3] + normact(aw*s_s32);
  }
  // h[64] = tanh(y2 @ Wm1 * s_s32)  (reuse S)
  #pragma unroll
  for (int k = 0; k < 64; k += 4){
    float ax=0.f, ay=0.f, az=0.f, aw=0.f;
    #pragma unroll
    for (int j = 0; j < 32; ++j){
      const float4 w4 = *(const float4*)&Wm1[j*64 + k];
      ax += y2[j]*w4.x; ay += y2[j]*w4.y; az += y2[j]*w4.z; aw += y2[j]*w4.w;
    }
    S[k]   = tanh_fast(ax*s_s32);
    S[k+1] = tanh_fast(ay*s_s32);
    S[k+2] = tanh_fast(az*s_s32);
    S[k+3] = tanh_fast(aw*s_s32);
  }
  // g[32] = tanh(h @ Wm2 * s_s64)  (reuse a); out = g @ Wm3 * s_s32
  float acc = 0.f;
  #pragma unroll
  for (int k = 0; k < 32; k += 4){
    float ax=0.f, ay=0.f, az=0.f, aw=0.f;
    #pragma unroll
    for (int j = 0; j < 64; ++j){
      const float4 w4 = *(const float4*)&Wm2[j*32 + k];
      ax += S[j]*w4.x; ay += S[j]*w4.y; az += S[j]*w4.z; aw += S[j]*w4.w;
    }
    acc += tanh_fast(ax*s_s64) * Wm3[k];
    acc += tanh_fast(ay*s_s64) * Wm3[k+1];
    acc += tanh_fast(az*s_s64) * Wm3[k+2];
    acc += tanh_fast(aw*s_s64) * Wm3[k+3];
  }
  out[n] = acc * s_s32;
}

extern "C" void kernel_launch(void* const* d_in, const int* in_sizes, int n_in,
                              void* d_out, int out_size, void* d_ws, size_t ws_size,
                              hipStream_t stream) {
  const float* coords   = (const float*)d_in[0];
  const int*   species  = (const int*)  d_in[1];
  const int*   ei       = (const int*)  d_in[2];
  const float* Wna      = (const float*)d_in[4];
  const float* Wlin1    = (const float*)d_in[5];
  const float* Wr1      = (const float*)d_in[6];
  const float* Wr2      = (const float*)d_in[7];
  const float* Wr3      = (const float*)d_in[8];
  const float* W2s      = (const float*)d_in[9];
  const float* Wsc      = (const float*)d_in[11];
  const float* Wfin     = (const float*)d_in[12];
  const float* Wr       = (const float*)d_in[13];
  const float* Wm1      = (const float*)d_in[14];
  const float* Wm2      = (const float*)d_in[15];
  const float* Wm3      = (const float*)d_in[16];
  float* out = (float*)d_out;

  const int N = in_sizes[1];
  const int E = in_sizes[2] / 2;

  char* ws = (char*)d_ws;
  size_t offA   = 0;                               // agg [N*32] f32 (12.8 MB)
  size_t offX1  = offA  + (size_t)N*32*4;          // x1tab 512B
  size_t offSC  = offX1 + 512;                     // sctab 1024B
  size_t offTAB = offSC + 1024;                    // tab (NTAB+2)*4*32 f32 (~2.1 MB)

  float* agg   = (float*)(ws + offA);
  float* x1tab = (float*)(ws + offX1);
  float* sctab = (float*)(ws + offSC);
  float* tab   = (float*)(ws + offTAB);

  hipMemsetAsync(agg, 0, (size_t)N*32*4, stream);

  k_pre<<<1, 256, 0, stream>>>(Wna, Wlin1, Wsc, x1tab, sctab);
  k_tab<<<(NTAB + 256) / 256, 256, 0, stream>>>(Wr1, Wr2, Wr3, x1tab, tab);
  k_edge2<<<(E + 255) / 256, 256, 0, stream>>>(coords, ei, species, tab, agg, E);
  k_node<<<(N + 255) / 256, 256, 0, stream>>>(agg, sctab, species, W2s, Wfin,
                                              Wr, Wm1, Wm2, Wm3, out, N);
}

// Round 4
// 533.503 us; speedup vs baseline: 3.0782x; 2.7437x over previous
//
#include <hip/hip_runtime.h>
#include <math.h>

#define RMAX 4.0f
#define NTAB 4096   // intervals over [0,4); rows 0..4096 built (+pad)

__device__ __forceinline__ float tanh_fast(float x){
  float e = __expf(2.0f * x);
  return 1.0f - 2.0f / (e + 1.0f);
}
__device__ __forceinline__ float normact(float s){
  float ns = fabsf(s);
  return s * tanh_fast(ns) / (ns + 1e-8f);
}

// shared live-edge predicate: MUST be identical in k_hist and k_build
__device__ __forceinline__ bool edge_r2(const float* __restrict__ coords,
                                        int s, int d, float& r2){
  float3 cs = *(const float3*)(coords + 3*s);
  float3 cd = *(const float3*)(coords + 3*d);
  float dx = cd.x - cs.x, dy = cd.y - cs.y, dz = cd.z - cs.z;
  r2 = dx*dx + dy*dy + dz*dz + 1e-8f;
  return r2 < RMAX*RMAX;
}

// ---------------- precompute per-species tables ----------------
__global__ void k_pre(const float* __restrict__ Wna, const float* __restrict__ Wlin1,
                      const float* __restrict__ Wsc,
                      float* __restrict__ x1tab, float* __restrict__ sctab){
  int id = threadIdx.x;
  if (id < 128){
    int c = id >> 5, j = id & 31;
    float acc = 0.f;
    for (int i = 0; i < 32; ++i) acc += Wna[c*32+i] * Wlin1[i*32+j];
    x1tab[id] = acc * (0.5f * 0.17677669529663687f);
  }
  if (id < 256){
    int c = id >> 6, k = id & 63;
    float acc = 0.f;
    for (int i = 0; i < 32; ++i) acc += Wna[c*32+i] * Wsc[(i*4+c)*64+k];
    sctab[id] = acc * (0.5f * 0.08838834764831843f);
  }
}

// ---------------- build radial table: tab[(i*4+c)*32+g] = w(r_i)[g]*x1tab[c][g] ----
__global__ void __launch_bounds__(256) k_tab(
    const float* __restrict__ Wr1, const float* __restrict__ Wr2,
    const float* __restrict__ Wr3, const float* __restrict__ x1tab,
    float* __restrict__ tab){
  __shared__ float sW1[8*64];
  __shared__ float sW2T[64*64];
  __shared__ float sW3[64*32];
  __shared__ float sX1[4*32];
  int t = threadIdx.x;
  for (int i = t; i < 512; i += 256) sW1[i] = Wr1[i] * 0.3535533905932738f;
  for (int i = t; i < 4096; i += 256){ int rr = i >> 6, cc = i & 63; sW2T[cc*64+rr] = Wr2[i] * 0.125f; }
  for (int i = t; i < 2048; i += 256){ int rr = i >> 5, cc = i & 31; sW3[i] = Wr3[rr*64+cc] * 0.125f; }
  for (int i = t; i < 128; i += 256) sX1[i] = x1tab[i];
  __syncthreads();
  int i = blockIdx.x * 256 + t;
  if (i > NTAB) return;
  float r = fmaxf((float)i * (RMAX / (float)NTAB), 1e-6f);

  float u = r * 0.25f;
  float u2 = u*u, u4 = u2*u2, u6 = u4*u2;
  float fc = 1.0f + u6 * (-28.0f + u * (48.0f - 21.0f * u));
  float pref = 0.5f / r * fc;
  float ea[8];
  #pragma unroll
  for (int k = 1; k <= 8; ++k) ea[k-1] = __sinf(0.78539816339744831f * r * (float)k) * pref;

  float h1[64];
  #pragma unroll
  for (int j = 0; j < 64; j += 4){
    float ax = 0.f, ay = 0.f, az = 0.f, aw = 0.f;
    #pragma unroll
    for (int k = 0; k < 8; ++k){
      const float4 w4 = *(const float4*)&sW1[k*64 + j];
      ax += ea[k]*w4.x; ay += ea[k]*w4.y; az += ea[k]*w4.z; aw += ea[k]*w4.w;
    }
    h1[j]   = tanh_fast(ax); h1[j+1] = tanh_fast(ay);
    h1[j+2] = tanh_fast(az); h1[j+3] = tanh_fast(aw);
  }

  float wsx[8], wsy[8], wsz[8], wsw[8];
  #pragma unroll
  for (int g = 0; g < 8; ++g){ wsx[g]=0.f; wsy[g]=0.f; wsz[g]=0.f; wsw[g]=0.f; }
  for (int j = 0; j < 64; ++j){
    float ax = 0.f, ay = 0.f, az = 0.f, aw = 0.f;
    #pragma unroll
    for (int k = 0; k < 64; k += 4){
      const float4 w4 = *(const float4*)&sW2T[j*64 + k];
      ax += h1[k]*w4.x; ay += h1[k+1]*w4.y; az += h1[k+2]*w4.z; aw += h1[k+3]*w4.w;
    }
    float tj = tanh_fast(ax + ay + az + aw);
    #pragma unroll
    for (int g = 0; g < 8; ++g){
      const float4 w4 = *(const float4*)&sW3[j*32 + g*4];
      wsx[g] += tj*w4.x; wsy[g] += tj*w4.y; wsz[g] += tj*w4.z; wsw[g] += tj*w4.w;
    }
  }

  #pragma unroll
  for (int c = 0; c < 4; ++c){
    float* row = tab + ((size_t)i*4 + c)*32;
    #pragma unroll
    for (int g = 0; g < 8; ++g){
      const float4 xv = *(const float4*)&sX1[c*32 + g*4];
      row[g*4+0] = wsx[g]*xv.x;
      row[g*4+1] = wsy[g]*xv.y;
      row[g*4+2] = wsz[g]*xv.z;
      row[g*4+3] = wsw[g]*xv.w;
    }
  }
}

// ---------------- CSR pass 1: live-edge histogram by dst ----------------
__global__ void __launch_bounds__(256) k_hist(
    const float* __restrict__ coords, const int* __restrict__ ei,
    int* __restrict__ hist, int E){
  int i = blockIdx.x * blockDim.x + threadIdx.x;
  if (i >= E) return;
  int s = ei[i], d = ei[E + i];
  float r2;
  if (edge_r2(coords, s, d, r2)) atomicAdd(&hist[d], 1);
}

// ---------------- CSR pass 2: exclusive scan (single block, 1024 thr) ----------
__global__ void __launch_bounds__(1024) k_scan(
    const int* __restrict__ hist, int* __restrict__ row, int N){
  __shared__ int sdata[1024];
  int t = threadIdx.x;
  int chunk = (N + 1023) / 1024;
  int lo = t * chunk, hi = min(lo + chunk, N);
  int sum = 0;
  for (int i = lo; i < hi; ++i) sum += hist[i];
  sdata[t] = sum;
  __syncthreads();
  for (int off = 1; off < 1024; off <<= 1){
    int v = (t >= off) ? sdata[t - off] : 0;
    __syncthreads();
    sdata[t] += v;
    __syncthreads();
  }
  int base = (t > 0) ? sdata[t - 1] : 0;
  for (int i = lo; i < hi; ++i){
    row[i] = base;
    base += hist[i];
  }
}

// ---------------- CSR pass 3: scatter payloads (r packed with species) --------
// after this kernel, row[d] == original row[d] + hist[d] (== segment end)
__global__ void __launch_bounds__(256) k_build(
    const float* __restrict__ coords, const int* __restrict__ ei,
    const int* __restrict__ species, int* __restrict__ row,
    unsigned* __restrict__ pay, int E){
  int i = blockIdx.x * blockDim.x + threadIdx.x;
  if (i >= E) return;
  int s = ei[i], d = ei[E + i];
  float r2;
  if (!edge_r2(coords, s, d, r2)) return;
  float r = sqrtf(r2);
  unsigned u = (__float_as_uint(r) & ~3u) | (unsigned)species[s];
  int pos = atomicAdd(&row[d], 1);
  pay[pos] = u;
}

// ---------------- fused gather + node tail: one thread per node ----------------
__global__ void __launch_bounds__(256) k_gather_node(
    const int* __restrict__ row, const int* __restrict__ hist,
    const unsigned* __restrict__ pay, const float* __restrict__ tab,
    const float* __restrict__ sctab, const int* __restrict__ species,
    const float* __restrict__ W2s, const float* __restrict__ Wfin,
    const float* __restrict__ Wr,  const float* __restrict__ Wm1,
    const float* __restrict__ Wm2, const float* __restrict__ Wm3,
    float* __restrict__ out, int N){
  const float s_16s32 = 0.0625f * 0.17677669529663687f;
  const float s_s64   = 0.125f;
  const float s_s32   = 0.17677669529663687f;
  int n = blockIdx.x * 256 + threadIdx.x;
  if (n >= N) return;
  int c = species[n];

  // ---- gather: sum messages over in-edges in registers ----
  float a[32];
  #pragma unroll
  for (int j = 0; j < 32; ++j) a[j] = 0.f;
  int end = row[n];             // post-build value = segment end
  int start = end - hist[n];
  for (int e = start; e < end; ++e){
    unsigned u = pay[e];
    int cc = (int)(u & 3u);
    float r = __uint_as_float(u & ~3u);
    float tt = r * ((float)NTAB / RMAX);
    int i0 = min((int)tt, NTAB - 1);
    float f = tt - (float)i0;
    const float4* r0 = (const float4*)(tab + ((size_t)i0*4 + cc)*32);
    const float4* r1 = r0 + 32;   // next r row (+4*32 floats)
    #pragma unroll
    for (int g = 0; g < 8; ++g){
      float4 p = r0[g], q = r1[g];
      a[g*4+0] += p.x + f*(q.x - p.x);
      a[g*4+1] += p.y + f*(q.y - p.y);
      a[g*4+2] += p.z + f*(q.z - p.z);
      a[g*4+3] += p.w + f*(q.w - p.w);
    }
  }

  // ---- node tail (identical math to round-3 k_node) ----
  float S[64];
  #pragma unroll
  for (int k = 0; k < 64; k += 4){
    float ax=0.f, ay=0.f, az=0.f, aw=0.f;
    #pragma unroll
    for (int j = 0; j < 32; ++j){
      const float4 w4 = *(const float4*)&W2s[j*64 + k];
      ax += a[j]*w4.x; ay += a[j]*w4.y; az += a[j]*w4.z; aw += a[j]*w4.w;
    }
    const float4 b4 = *(const float4*)&sctab[c*64 + k];
    S[k]   = normact(ax*s_16s32 + b4.x);
    S[k+1] = normact(ay*s_16s32 + b4.y);
    S[k+2] = normact(az*s_16s32 + b4.z);
    S[k+3] = normact(aw*s_16s32 + b4.w);
  }
  #pragma unroll
  for (int k = 0; k < 32; k += 4){
    float ax=0.f, ay=0.f, az=0.f, aw=0.f;
    #pragma unroll
    for (int j = 0; j < 64; ++j){
      const float4 w4 = *(const float4*)&Wfin[j*32 + k];
      ax += S[j]*w4.x; ay += S[j]*w4.y; az += S[j]*w4.z; aw += S[j]*w4.w;
    }
    a[k]   = normact(ax*s_s64);
    a[k+1] = normact(ay*s_s64);
    a[k+2] = normact(az*s_s64);
    a[k+3] = normact(aw*s_s64);
  }
  float y2[32];
  #pragma unroll
  for (int k = 0; k < 32; k += 4){
    float ax=0.f, ay=0.f, az=0.f, aw=0.f;
    #pragma unroll
    for (int j = 0; j < 32; ++j){
      const float4 w4 = *(const float4*)&Wr[j*32 + k];
      ax += a[j]*w4.x; ay += a[j]*w4.y; az += a[j]*w4.z; aw += a[j]*w4.w;
    }
    y2[k]   = a[k]   + normact(ax*s_s32);
    y2[k+1] = a[k+1] + normact(ay*s_s32);
    y2[k+2] = a[k+2] + normact(az*s_s32);
    y2[k+3] = a[k+3] + normact(aw*s_s32);
  }
  #pragma unroll
  for (int k = 0; k < 64; k += 4){
    float ax=0.f, ay=0.f, az=0.f, aw=0.f;
    #pragma unroll
    for (int j = 0; j < 32; ++j){
      const float4 w4 = *(const float4*)&Wm1[j*64 + k];
      ax += y2[j]*w4.x; ay += y2[j]*w4.y; az += y2[j]*w4.z; aw += y2[j]*w4.w;
    }
    S[k]   = tanh_fast(ax*s_s32);
    S[k+1] = tanh_fast(ay*s_s32);
    S[k+2] = tanh_fast(az*s_s32);
    S[k+3] = tanh_fast(aw*s_s32);
  }
  float acc = 0.f;
  #pragma unroll
  for (int k = 0; k < 32; k += 4){
    float ax=0.f, ay=0.f, az=0.f, aw=0.f;
    #pragma unroll
    for (int j = 0; j < 64; ++j){
      const float4 w4 = *(const float4*)&Wm2[j*32 + k];
      ax += S[j]*w4.x; ay += S[j]*w4.y; az += S[j]*w4.z; aw += S[j]*w4.w;
    }
    acc += tanh_fast(ax*s_s64) * Wm3[k];
    acc += tanh_fast(ay*s_s64) * Wm3[k+1];
    acc += tanh_fast(az*s_s64) * Wm3[k+2];
    acc += tanh_fast(aw*s_s64) * Wm3[k+3];
  }
  out[n] = acc * s_s32;
}

extern "C" void kernel_launch(void* const* d_in, const int* in_sizes, int n_in,
                              void* d_out, int out_size, void* d_ws, size_t ws_size,
                              hipStream_t stream) {
  const float* coords   = (const float*)d_in[0];
  const int*   species  = (const int*)  d_in[1];
  const int*   ei       = (const int*)  d_in[2];
  const float* Wna      = (const float*)d_in[4];
  const float* Wlin1    = (const float*)d_in[5];
  const float* Wr1      = (const float*)d_in[6];
  const float* Wr2      = (const float*)d_in[7];
  const float* Wr3      = (const float*)d_in[8];
  const float* W2s      = (const float*)d_in[9];
  const float* Wsc      = (const float*)d_in[11];
  const float* Wfin     = (const float*)d_in[12];
  const float* Wr       = (const float*)d_in[13];
  const float* Wm1      = (const float*)d_in[14];
  const float* Wm2      = (const float*)d_in[15];
  const float* Wm3      = (const float*)d_in[16];
  float* out = (float*)d_out;

  const int N = in_sizes[1];
  const int E = in_sizes[2] / 2;

  char* ws = (char*)d_ws;
  size_t offX1  = 0;                                 // x1tab 512B
  size_t offSC  = offX1 + 512;                       // sctab 1024B
  size_t offTAB = offSC + 1024;                      // tab (NTAB+2)*4*32 f32 (~2.1MB)
  size_t offH   = offTAB + (size_t)(NTAB+2)*128*4;   // hist [N] int
  size_t offR   = offH + (size_t)N*4;                // row  [N] int
  size_t offP   = offR + (size_t)N*4;                // pay  [E] u32

  float*    x1tab = (float*)(ws + offX1);
  float*    sctab = (float*)(ws + offSC);
  float*    tab   = (float*)(ws + offTAB);
  int*      hist  = (int*)  (ws + offH);
  int*      rowp  = (int*)  (ws + offR);
  unsigned* pay   = (unsigned*)(ws + offP);

  hipMemsetAsync(hist, 0, (size_t)N*4, stream);

  k_pre<<<1, 256, 0, stream>>>(Wna, Wlin1, Wsc, x1tab, sctab);
  k_tab<<<(NTAB + 256) / 256, 256, 0, stream>>>(Wr1, Wr2, Wr3, x1tab, tab);

  int blkE = (E + 255) / 256;
  k_hist<<<blkE, 256, 0, stream>>>(coords, ei, hist, E);
  k_scan<<<1, 1024, 0, stream>>>(hist, rowp, N);
  k_build<<<blkE, 256, 0, stream>>>(coords, ei, species, rowp, pay, E);
  k_gather_node<<<(N + 255) / 256, 256, 0, stream>>>(rowp, hist, pay, tab, sctab,
                                                     species, W2s, Wfin, Wr, Wm1,
                                                     Wm2, Wm3, out, N);
}

// Round 5
// 445.428 us; speedup vs baseline: 3.6869x; 1.1977x over previous
//
#include <hip/hip_runtime.h>
#include <math.h>

#define RMAX 4.0f
#define NTAB 4096    // intervals over [0,4); rows 0..4096 built (+pad)
#define DEGCAP 48    // max live in-degree bucket capacity (P(exceed) ~ 1e-11)

__device__ __forceinline__ float tanh_fast(float x){
  float e = __expf(2.0f * x);
  return 1.0f - 2.0f / (e + 1.0f);
}
__device__ __forceinline__ float normact(float s){
  float ns = fabsf(s);
  return s * tanh_fast(ns) / (ns + 1e-8f);
}

// ---------------- precompute per-species tables ----------------
__global__ void k_pre(const float* __restrict__ Wna, const float* __restrict__ Wlin1,
                      const float* __restrict__ Wsc,
                      float* __restrict__ x1tab, float* __restrict__ sctab){
  int id = threadIdx.x;
  if (id < 128){
    int c = id >> 5, j = id & 31;
    float acc = 0.f;
    for (int i = 0; i < 32; ++i) acc += Wna[c*32+i] * Wlin1[i*32+j];
    x1tab[id] = acc * (0.5f * 0.17677669529663687f);
  }
  if (id < 256){
    int c = id >> 6, k = id & 63;
    float acc = 0.f;
    for (int i = 0; i < 32; ++i) acc += Wna[c*32+i] * Wsc[(i*4+c)*64+k];
    sctab[id] = acc * (0.5f * 0.08838834764831843f);
  }
}

// ---------------- build radial table: tab[(i*4+c)*32+g] = w(r_i)[g]*x1tab[c][g] ----
__global__ void __launch_bounds__(256) k_tab(
    const float* __restrict__ Wr1, const float* __restrict__ Wr2,
    const float* __restrict__ Wr3, const float* __restrict__ x1tab,
    float* __restrict__ tab){
  __shared__ float sW1[8*64];
  __shared__ float sW2T[64*64];
  __shared__ float sW3[64*32];
  __shared__ float sX1[4*32];
  int t = threadIdx.x;
  for (int i = t; i < 512; i += 256) sW1[i] = Wr1[i] * 0.3535533905932738f;
  for (int i = t; i < 4096; i += 256){ int rr = i >> 6, cc = i & 63; sW2T[cc*64+rr] = Wr2[i] * 0.125f; }
  for (int i = t; i < 2048; i += 256){ int rr = i >> 5, cc = i & 31; sW3[i] = Wr3[rr*64+cc] * 0.125f; }
  for (int i = t; i < 128; i += 256) sX1[i] = x1tab[i];
  __syncthreads();
  int i = blockIdx.x * 256 + t;
  if (i > NTAB) return;
  float r = fmaxf((float)i * (RMAX / (float)NTAB), 1e-6f);

  float u = r * 0.25f;
  float u2 = u*u, u4 = u2*u2, u6 = u4*u2;
  float fc = 1.0f + u6 * (-28.0f + u * (48.0f - 21.0f * u));
  float pref = 0.5f / r * fc;
  float ea[8];
  #pragma unroll
  for (int k = 1; k <= 8; ++k) ea[k-1] = __sinf(0.78539816339744831f * r * (float)k) * pref;

  float h1[64];
  #pragma unroll
  for (int j = 0; j < 64; j += 4){
    float ax = 0.f, ay = 0.f, az = 0.f, aw = 0.f;
    #pragma unroll
    for (int k = 0; k < 8; ++k){
      const float4 w4 = *(const float4*)&sW1[k*64 + j];
      ax += ea[k]*w4.x; ay += ea[k]*w4.y; az += ea[k]*w4.z; aw += ea[k]*w4.w;
    }
    h1[j]   = tanh_fast(ax); h1[j+1] = tanh_fast(ay);
    h1[j+2] = tanh_fast(az); h1[j+3] = tanh_fast(aw);
  }

  float wsx[8], wsy[8], wsz[8], wsw[8];
  #pragma unroll
  for (int g = 0; g < 8; ++g){ wsx[g]=0.f; wsy[g]=0.f; wsz[g]=0.f; wsw[g]=0.f; }
  for (int j = 0; j < 64; ++j){
    float ax = 0.f, ay = 0.f, az = 0.f, aw = 0.f;
    #pragma unroll
    for (int k = 0; k < 64; k += 4){
      const float4 w4 = *(const float4*)&sW2T[j*64 + k];
      ax += h1[k]*w4.x; ay += h1[k+1]*w4.y; az += h1[k+2]*w4.z; aw += h1[k+3]*w4.w;
    }
    float tj = tanh_fast(ax + ay + az + aw);
    #pragma unroll
    for (int g = 0; g < 8; ++g){
      const float4 w4 = *(const float4*)&sW3[j*32 + g*4];
      wsx[g] += tj*w4.x; wsy[g] += tj*w4.y; wsz[g] += tj*w4.z; wsw[g] += tj*w4.w;
    }
  }

  #pragma unroll
  for (int c = 0; c < 4; ++c){
    float* row = tab + ((size_t)i*4 + c)*32;
    #pragma unroll
    for (int g = 0; g < 8; ++g){
      const float4 xv = *(const float4*)&sX1[c*32 + g*4];
      row[g*4+0] = wsx[g]*xv.x;
      row[g*4+1] = wsy[g]*xv.y;
      row[g*4+2] = wsz[g]*xv.z;
      row[g*4+3] = wsw[g]*xv.w;
    }
  }
}

// ---------------- single-pass bucketed edge build ----------------
// pay[d*DEGCAP + slot] = r packed with species(src) in low 2 bits
__global__ void __launch_bounds__(256) k_edges(
    const float* __restrict__ coords, const int* __restrict__ ei,
    const int* __restrict__ species, int* __restrict__ hist,
    unsigned* __restrict__ pay, int E){
  int i = blockIdx.x * blockDim.x + threadIdx.x;
  if (i >= E) return;
  int s = ei[i], d = ei[E + i];
  float3 cs = *(const float3*)(coords + 3*s);
  float3 cd = *(const float3*)(coords + 3*d);
  float dx = cd.x - cs.x, dy = cd.y - cs.y, dz = cd.z - cs.z;
  float r2 = dx*dx + dy*dy + dz*dz + 1e-8f;
  if (r2 >= RMAX*RMAX) return;           // fcut=0 -> msg exactly 0
  float r = sqrtf(r2);
  unsigned u = (__float_as_uint(r) & ~3u) | (unsigned)species[s];
  int pos = atomicAdd(&hist[d], 1);
  if (pos < DEGCAP) pay[(size_t)d * DEGCAP + pos] = u;
}

// ---------------- fused gather + node tail: 4 lanes per node ----------------
__global__ void __launch_bounds__(256, 4) k_gather_node(
    const int* __restrict__ hist, const unsigned* __restrict__ pay,
    const float* __restrict__ tab, const float* __restrict__ sctab,
    const int* __restrict__ species,
    const float* __restrict__ W2s, const float* __restrict__ Wfin,
    const float* __restrict__ Wr,  const float* __restrict__ Wm1,
    const float* __restrict__ Wm2, const float* __restrict__ Wm3,
    float* __restrict__ out, int N){
  const float s_16s32 = 0.0625f * 0.17677669529663687f;
  const float s_s64   = 0.125f;
  const float s_s32   = 0.17677669529663687f;
  int gid = blockIdx.x * 256 + threadIdx.x;
  int n = gid >> 2;
  if (n >= N) return;
  int sub  = gid & 3;
  int lane = threadIdx.x & 63;
  int base = lane & ~3;     // absolute lane of sub==0 in this group

  // ---- gather: each lane sums a strided quarter of in-edges ----
  float a[32];
  #pragma unroll
  for (int j = 0; j < 32; ++j) a[j] = 0.f;
  int count = min(hist[n], DEGCAP);
  const unsigned* prow = pay + (size_t)n * DEGCAP;
  for (int e = sub; e < count; e += 4){
    unsigned u = prow[e];
    int cc = (int)(u & 3u);
    float r = __uint_as_float(u & ~3u);
    float tt = r * ((float)NTAB / RMAX);
    int i0 = min((int)tt, NTAB - 1);
    float f = tt - (float)i0;
    const float4* r0 = (const float4*)(tab + ((size_t)i0*4 + cc)*32);
    const float4* r1 = r0 + 32;          // next r row (+4*32 floats)
    #pragma unroll
    for (int g = 0; g < 8; ++g){
      float4 p = r0[g], q = r1[g];
      a[g*4+0] += p.x + f*(q.x - p.x);
      a[g*4+1] += p.y + f*(q.y - p.y);
      a[g*4+2] += p.z + f*(q.z - p.z);
      a[g*4+3] += p.w + f*(q.w - p.w);
    }
  }
  // 4-lane tree reduce -> all 4 lanes hold the identical full sum
  #pragma unroll
  for (int j = 0; j < 32; ++j){
    a[j] += __shfl_xor(a[j], 1);
    a[j] += __shfl_xor(a[j], 2);
  }

  int c = species[n];
  float own[16];

  // ---- L1: S[64] = normact(a @ W2s * s + sctab[c]); lane owns 16 outputs ----
  #pragma unroll
  for (int q = 0; q < 4; ++q){
    int k = sub*16 + q*4;
    float ax=0.f, ay=0.f, az=0.f, aw=0.f;
    #pragma unroll
    for (int j = 0; j < 32; ++j){
      const float4 w4 = *(const float4*)&W2s[j*64 + k];
      ax += a[j]*w4.x; ay += a[j]*w4.y; az += a[j]*w4.z; aw += a[j]*w4.w;
    }
    const float4 b4 = *(const float4*)&sctab[c*64 + k];
    own[q*4+0] = normact(ax*s_16s32 + b4.x);
    own[q*4+1] = normact(ay*s_16s32 + b4.y);
    own[q*4+2] = normact(az*s_16s32 + b4.z);
    own[q*4+3] = normact(aw*s_16s32 + b4.w);
  }
  float S[64];
  #pragma unroll
  for (int s4 = 0; s4 < 4; ++s4)
    #pragma unroll
    for (int t = 0; t < 16; ++t)
      S[s4*16 + t] = __shfl(own[t], base + s4);

  // ---- L2: y[32] = normact(S @ Wfin * s_s64); lane owns 8 ----
  #pragma unroll
  for (int q = 0; q < 2; ++q){
    int k = sub*8 + q*4;
    float ax=0.f, ay=0.f, az=0.f, aw=0.f;
    #pragma unroll
    for (int j = 0; j < 64; ++j){
      const float4 w4 = *(const float4*)&Wfin[j*32 + k];
      ax += S[j]*w4.x; ay += S[j]*w4.y; az += S[j]*w4.z; aw += S[j]*w4.w;
    }
    own[q*4+0] = normact(ax*s_s64);
    own[q*4+1] = normact(ay*s_s64);
    own[q*4+2] = normact(az*s_s64);
    own[q*4+3] = normact(aw*s_s64);
  }
  float y[32];
  #pragma unroll
  for (int s4 = 0; s4 < 4; ++s4)
    #pragma unroll
    for (int t = 0; t < 8; ++t)
      y[s4*8 + t] = __shfl(own[t], base + s4);

  // ---- L3: y2[32] = y + normact(y @ Wr * s_s32); lane owns 8 ----
  #pragma unroll
  for (int q = 0; q < 2; ++q){
    int k = sub*8 + q*4;
    float ax=0.f, ay=0.f, az=0.f, aw=0.f;
    #pragma unroll
    for (int j = 0; j < 32; ++j){
      const float4 w4 = *(const float4*)&Wr[j*32 + k];
      ax += y[j]*w4.x; ay += y[j]*w4.y; az += y[j]*w4.z; aw += y[j]*w4.w;
    }
    own[q*4+0] = y[k+0] + normact(ax*s_s32);
    own[q*4+1] = y[k+1] + normact(ay*s_s32);
    own[q*4+2] = y[k+2] + normact(az*s_s32);
    own[q*4+3] = y[k+3] + normact(aw*s_s32);
  }
  float y2[32];
  #pragma unroll
  for (int s4 = 0; s4 < 4; ++s4)
    #pragma unroll
    for (int t = 0; t < 8; ++t)
      y2[s4*8 + t] = __shfl(own[t], base + s4);

  // ---- L4: h[64] = tanh(y2 @ Wm1 * s_s32); lane owns 16 (reuse S) ----
  #pragma unroll
  for (int q = 0; q < 4; ++q){
    int k = sub*16 + q*4;
    float ax=0.f, ay=0.f, az=0.f, aw=0.f;
    #pragma unroll
    for (int j = 0; j < 32; ++j){
      const float4 w4 = *(const float4*)&Wm1[j*64 + k];
      ax += y2[j]*w4.x; ay += y2[j]*w4.y; az += y2[j]*w4.z; aw += y2[j]*w4.w;
    }
    own[q*4+0] = tanh_fast(ax*s_s32);
    own[q*4+1] = tanh_fast(ay*s_s32);
    own[q*4+2] = tanh_fast(az*s_s32);
    own[q*4+3] = tanh_fast(aw*s_s32);
  }
  #pragma unroll
  for (int s4 = 0; s4 < 4; ++s4)
    #pragma unroll
    for (int t = 0; t < 16; ++t)
      S[s4*16 + t] = __shfl(own[t], base + s4);

  // ---- L5: g = tanh(h @ Wm2 * s_s64); fold final dot with Wm3; reduce ----
  float acc = 0.f;
  #pragma unroll
  for (int q = 0; q < 2; ++q){
    int k = sub*8 + q*4;
    float ax=0.f, ay=0.f, az=0.f, aw=0.f;
    #pragma unroll
    for (int j = 0; j < 64; ++j){
      const float4 w4 = *(const float4*)&Wm2[j*32 + k];
      ax += S[j]*w4.x; ay += S[j]*w4.y; az += S[j]*w4.z; aw += S[j]*w4.w;
    }
    acc += tanh_fast(ax*s_s64) * Wm3[k+0];
    acc += tanh_fast(ay*s_s64) * Wm3[k+1];
    acc += tanh_fast(az*s_s64) * Wm3[k+2];
    acc += tanh_fast(aw*s_s64) * Wm3[k+3];
  }
  acc += __shfl_xor(acc, 1);
  acc += __shfl_xor(acc, 2);
  if (sub == 0) out[n] = acc * s_s32;
}

extern "C" void kernel_launch(void* const* d_in, const int* in_sizes, int n_in,
                              void* d_out, int out_size, void* d_ws, size_t ws_size,
                              hipStream_t stream) {
  const float* coords   = (const float*)d_in[0];
  const int*   species  = (const int*)  d_in[1];
  const int*   ei       = (const int*)  d_in[2];
  const float* Wna      = (const float*)d_in[4];
  const float* Wlin1    = (const float*)d_in[5];
  const float* Wr1      = (const float*)d_in[6];
  const float* Wr2      = (const float*)d_in[7];
  const float* Wr3      = (const float*)d_in[8];
  const float* W2s      = (const float*)d_in[9];
  const float* Wsc      = (const float*)d_in[11];
  const float* Wfin     = (const float*)d_in[12];
  const float* Wr       = (const float*)d_in[13];
  const float* Wm1      = (const float*)d_in[14];
  const float* Wm2      = (const float*)d_in[15];
  const float* Wm3      = (const float*)d_in[16];
  float* out = (float*)d_out;

  const int N = in_sizes[1];
  const int E = in_sizes[2] / 2;

  char* ws = (char*)d_ws;
  size_t offX1  = 0;                                 // x1tab 512B
  size_t offSC  = offX1 + 512;                       // sctab 1024B
  size_t offTAB = offSC + 1024;                      // tab (NTAB+2)*128 f32 (~2.1MB)
  size_t offH   = offTAB + (size_t)(NTAB+2)*128*4;   // hist [N] int
  size_t offP   = offH + (size_t)N*4;                // pay  [N*DEGCAP] u32 (~19.2MB)

  float*    x1tab = (float*)(ws + offX1);
  float*    sctab = (float*)(ws + offSC);
  float*    tab   = (float*)(ws + offTAB);
  int*      hist  = (int*)  (ws + offH);
  unsigned* pay   = (unsigned*)(ws + offP);

  hipMemsetAsync(hist, 0, (size_t)N*4, stream);

  k_pre<<<1, 256, 0, stream>>>(Wna, Wlin1, Wsc, x1tab, sctab);
  k_tab<<<(NTAB + 256) / 256, 256, 0, stream>>>(Wr1, Wr2, Wr3, x1tab, tab);
  k_edges<<<(E + 255) / 256, 256, 0, stream>>>(coords, ei, species, hist, pay, E);
  k_gather_node<<<((size_t)N*4 + 255) / 256, 256, 0, stream>>>(
      hist, pay, tab, sctab, species, W2s, Wfin, Wr, Wm1, Wm2, Wm3, out, N);
}

// Round 6
// 289.118 us; speedup vs baseline: 5.6802x; 1.5406x over previous
//
#include <hip/hip_runtime.h>
#include <math.h>

#define RMAX 4.0f
#define NTAB 4096    // intervals over [0,4); rows 0..4096 built (+pad)
#define DEGCAP 48    // max live in-degree bucket capacity (P(exceed) ~ 1e-11)

__device__ __forceinline__ float tanh_fast(float x){
  float e = __expf(2.0f * x);
  return 1.0f - 2.0f / (e + 1.0f);
}
__device__ __forceinline__ float normact(float s){
  float ns = fabsf(s);
  return s * tanh_fast(ns) / (ns + 1e-8f);
}

// ---------------- precompute per-species tables ----------------
__global__ void k_pre(const float* __restrict__ Wna, const float* __restrict__ Wlin1,
                      const float* __restrict__ Wsc,
                      float* __restrict__ x1tab, float* __restrict__ sctab){
  int id = threadIdx.x;
  if (id < 128){
    int c = id >> 5, j = id & 31;
    float acc = 0.f;
    for (int i = 0; i < 32; ++i) acc += Wna[c*32+i] * Wlin1[i*32+j];
    x1tab[id] = acc * (0.5f * 0.17677669529663687f);
  }
  if (id < 256){
    int c = id >> 6, k = id & 63;
    float acc = 0.f;
    for (int i = 0; i < 32; ++i) acc += Wna[c*32+i] * Wsc[(i*4+c)*64+k];
    sctab[id] = acc * (0.5f * 0.08838834764831843f);
  }
}

// ---------------- build radial table: tab[(i*4+c)*32+g] = w(r_i)[g]*x1tab[c][g] ----
__global__ void __launch_bounds__(256) k_tab(
    const float* __restrict__ Wr1, const float* __restrict__ Wr2,
    const float* __restrict__ Wr3, const float* __restrict__ x1tab,
    float* __restrict__ tab){
  __shared__ float sW1[8*64];
  __shared__ float sW2T[64*64];
  __shared__ float sW3[64*32];
  __shared__ float sX1[4*32];
  int t = threadIdx.x;
  for (int i = t; i < 512; i += 256) sW1[i] = Wr1[i] * 0.3535533905932738f;
  for (int i = t; i < 4096; i += 256){ int rr = i >> 6, cc = i & 63; sW2T[cc*64+rr] = Wr2[i] * 0.125f; }
  for (int i = t; i < 2048; i += 256){ int rr = i >> 5, cc = i & 31; sW3[i] = Wr3[rr*64+cc] * 0.125f; }
  for (int i = t; i < 128; i += 256) sX1[i] = x1tab[i];
  __syncthreads();
  int i = blockIdx.x * 256 + t;
  if (i > NTAB) return;
  float r = fmaxf((float)i * (RMAX / (float)NTAB), 1e-6f);

  float u = r * 0.25f;
  float u2 = u*u, u4 = u2*u2, u6 = u4*u2;
  float fc = 1.0f + u6 * (-28.0f + u * (48.0f - 21.0f * u));
  float pref = 0.5f / r * fc;
  float ea[8];
  #pragma unroll
  for (int k = 1; k <= 8; ++k) ea[k-1] = __sinf(0.78539816339744831f * r * (float)k) * pref;

  float h1[64];
  #pragma unroll
  for (int j = 0; j < 64; j += 4){
    float ax = 0.f, ay = 0.f, az = 0.f, aw = 0.f;
    #pragma unroll
    for (int k = 0; k < 8; ++k){
      const float4 w4 = *(const float4*)&sW1[k*64 + j];
      ax += ea[k]*w4.x; ay += ea[k]*w4.y; az += ea[k]*w4.z; aw += ea[k]*w4.w;
    }
    h1[j]   = tanh_fast(ax); h1[j+1] = tanh_fast(ay);
    h1[j+2] = tanh_fast(az); h1[j+3] = tanh_fast(aw);
  }

  float wsx[8], wsy[8], wsz[8], wsw[8];
  #pragma unroll
  for (int g = 0; g < 8; ++g){ wsx[g]=0.f; wsy[g]=0.f; wsz[g]=0.f; wsw[g]=0.f; }
  for (int j = 0; j < 64; ++j){
    float ax = 0.f, ay = 0.f, az = 0.f, aw = 0.f;
    #pragma unroll
    for (int k = 0; k < 64; k += 4){
      const float4 w4 = *(const float4*)&sW2T[j*64 + k];
      ax += h1[k]*w4.x; ay += h1[k+1]*w4.y; az += h1[k+2]*w4.z; aw += h1[k+3]*w4.w;
    }
    float tj = tanh_fast(ax + ay + az + aw);
    #pragma unroll
    for (int g = 0; g < 8; ++g){
      const float4 w4 = *(const float4*)&sW3[j*32 + g*4];
      wsx[g] += tj*w4.x; wsy[g] += tj*w4.y; wsz[g] += tj*w4.z; wsw[g] += tj*w4.w;
    }
  }

  #pragma unroll
  for (int c = 0; c < 4; ++c){
    float* row = tab + ((size_t)i*4 + c)*32;
    #pragma unroll
    for (int g = 0; g < 8; ++g){
      const float4 xv = *(const float4*)&sX1[c*32 + g*4];
      row[g*4+0] = wsx[g]*xv.x;
      row[g*4+1] = wsy[g]*xv.y;
      row[g*4+2] = wsz[g]*xv.z;
      row[g*4+3] = wsw[g]*xv.w;
    }
  }
}

// ---------------- single-pass bucketed edge build ----------------
// pay[d*DEGCAP + slot] = r packed with species(src) in low 2 bits
__global__ void __launch_bounds__(256) k_edges(
    const float* __restrict__ coords, const int* __restrict__ ei,
    const int* __restrict__ species, int* __restrict__ hist,
    unsigned* __restrict__ pay, int E){
  int i = blockIdx.x * blockDim.x + threadIdx.x;
  if (i >= E) return;
  int s = ei[i], d = ei[E + i];
  float3 cs = *(const float3*)(coords + 3*s);
  float3 cd = *(const float3*)(coords + 3*d);
  float dx = cd.x - cs.x, dy = cd.y - cs.y, dz = cd.z - cs.z;
  float r2 = dx*dx + dy*dy + dz*dz + 1e-8f;
  if (r2 >= RMAX*RMAX) return;           // fcut=0 -> msg exactly 0
  float r = sqrtf(r2);
  unsigned u = (__float_as_uint(r) & ~3u) | (unsigned)species[s];
  int pos = atomicAdd(&hist[d], 1);
  if (pos < DEGCAP) pay[(size_t)d * DEGCAP + pos] = u;
}

// ---------------- fused gather + node tail: 4 lanes per node ----------------
// Each lane keeps ONLY its owned output slice per layer; consumer layers
// stream cross-lane values via __shfl inside the dot loop (no full arrays
// -> no spills; round-5 post-mortem: materializing S[64]/y[32]/y2[32]
// spilled ~650 MB of scratch traffic).
__global__ void __launch_bounds__(256) k_gather_node(
    const int* __restrict__ hist, const unsigned* __restrict__ pay,
    const float* __restrict__ tab, const float* __restrict__ sctab,
    const int* __restrict__ species,
    const float* __restrict__ W2s, const float* __restrict__ Wfin,
    const float* __restrict__ Wr,  const float* __restrict__ Wm1,
    const float* __restrict__ Wm2, const float* __restrict__ Wm3,
    float* __restrict__ out, int N){
  const float s_16s32 = 0.0625f * 0.17677669529663687f;
  const float s_s64   = 0.125f;
  const float s_s32   = 0.17677669529663687f;
  int gid = blockIdx.x * 256 + threadIdx.x;
  int n = gid >> 2;
  if (n >= N) return;
  int sub  = gid & 3;
  int base = (threadIdx.x & 63) & ~3;   // lane of sub==0 in this 4-lane group

  // ---- gather: each lane sums a strided quarter of in-edges ----
  float a[32];
  #pragma unroll
  for (int j = 0; j < 32; ++j) a[j] = 0.f;
  int count = min(hist[n], DEGCAP);
  const unsigned* prow = pay + (size_t)n * DEGCAP;
  for (int e = sub; e < count; e += 4){
    unsigned u = prow[e];
    int cc = (int)(u & 3u);
    float r = __uint_as_float(u & ~3u);
    float tt = r * ((float)NTAB / RMAX);
    int i0 = min((int)tt, NTAB - 1);
    float f = tt - (float)i0;
    const float4* r0 = (const float4*)(tab + ((size_t)i0*4 + cc)*32);
    const float4* r1 = r0 + 32;          // next r row (+4*32 floats)
    #pragma unroll
    for (int g = 0; g < 8; ++g){
      float4 p = r0[g], q = r1[g];
      a[g*4+0] += p.x + f*(q.x - p.x);
      a[g*4+1] += p.y + f*(q.y - p.y);
      a[g*4+2] += p.z + f*(q.z - p.z);
      a[g*4+3] += p.w + f*(q.w - p.w);
    }
  }
  // 4-lane tree reduce -> all 4 lanes hold the identical full a[32]
  #pragma unroll
  for (int j = 0; j < 32; ++j){
    a[j] += __shfl_xor(a[j], 1);
    a[j] += __shfl_xor(a[j], 2);
  }

  int c = species[n];

  // ---- L1: S[64]; lane owns k in [sub*16, sub*16+16) ----
  float sOwn[16];
  #pragma unroll
  for (int q = 0; q < 4; ++q){
    int k = sub*16 + q*4;
    float ax=0.f, ay=0.f, az=0.f, aw=0.f;
    #pragma unroll
    for (int j = 0; j < 32; ++j){
      const float4 w4 = *(const float4*)&W2s[j*64 + k];
      ax += a[j]*w4.x; ay += a[j]*w4.y; az += a[j]*w4.z; aw += a[j]*w4.w;
    }
    const float4 b4 = *(const float4*)&sctab[c*64 + k];
    sOwn[q*4+0] = normact(ax*s_16s32 + b4.x);
    sOwn[q*4+1] = normact(ay*s_16s32 + b4.y);
    sOwn[q*4+2] = normact(az*s_16s32 + b4.z);
    sOwn[q*4+3] = normact(aw*s_16s32 + b4.w);
  }

  // ---- L2: y[32] = normact(S @ Wfin); lane owns 8; stream S via shfl ----
  int k8 = sub*8;
  float acc8[8];
  #pragma unroll
  for (int q = 0; q < 8; ++q) acc8[q] = 0.f;
  #pragma unroll
  for (int s4 = 0; s4 < 4; ++s4){
    #pragma unroll
    for (int t = 0; t < 16; ++t){
      float sval = __shfl(sOwn[t], base + s4);
      const int j = s4*16 + t;
      const float4 w0 = *(const float4*)&Wfin[j*32 + k8];
      const float4 w1 = *(const float4*)&Wfin[j*32 + k8 + 4];
      acc8[0] += sval*w0.x; acc8[1] += sval*w0.y; acc8[2] += sval*w0.z; acc8[3] += sval*w0.w;
      acc8[4] += sval*w1.x; acc8[5] += sval*w1.y; acc8[6] += sval*w1.z; acc8[7] += sval*w1.w;
    }
  }
  float yOwn[8];
  #pragma unroll
  for (int q = 0; q < 8; ++q) yOwn[q] = normact(acc8[q]*s_s64);

  // ---- L3: y2[32] = y + normact(y @ Wr); lane owns 8 ----
  #pragma unroll
  for (int q = 0; q < 8; ++q) acc8[q] = 0.f;
  #pragma unroll
  for (int s4 = 0; s4 < 4; ++s4){
    #pragma unroll
    for (int t = 0; t < 8; ++t){
      float yval = __shfl(yOwn[t], base + s4);
      const int j = s4*8 + t;
      const float4 w0 = *(const float4*)&Wr[j*32 + k8];
      const float4 w1 = *(const float4*)&Wr[j*32 + k8 + 4];
      acc8[0] += yval*w0.x; acc8[1] += yval*w0.y; acc8[2] += yval*w0.z; acc8[3] += yval*w0.w;
      acc8[4] += yval*w1.x; acc8[5] += yval*w1.y; acc8[6] += yval*w1.z; acc8[7] += yval*w1.w;
    }
  }
  float y2Own[8];
  #pragma unroll
  for (int q = 0; q < 8; ++q) y2Own[q] = yOwn[q] + normact(acc8[q]*s_s32);

  // ---- L4: h[64] = tanh(y2 @ Wm1); lane owns 16 ----
  float acc16[16];
  #pragma unroll
  for (int t = 0; t < 16; ++t) acc16[t] = 0.f;
  int k16 = sub*16;
  #pragma unroll
  for (int s4 = 0; s4 < 4; ++s4){
    #pragma unroll
    for (int t = 0; t < 8; ++t){
      float yv = __shfl(y2Own[t], base + s4);
      const int j = s4*8 + t;
      const float4 w0 = *(const float4*)&Wm1[j*64 + k16];
      const float4 w1 = *(const float4*)&Wm1[j*64 + k16 + 4];
      const float4 w2 = *(const float4*)&Wm1[j*64 + k16 + 8];
      const float4 w3 = *(const float4*)&Wm1[j*64 + k16 + 12];
      acc16[0]  += yv*w0.x; acc16[1]  += yv*w0.y; acc16[2]  += yv*w0.z; acc16[3]  += yv*w0.w;
      acc16[4]  += yv*w1.x; acc16[5]  += yv*w1.y; acc16[6]  += yv*w1.z; acc16[7]  += yv*w1.w;
      acc16[8]  += yv*w2.x; acc16[9]  += yv*w2.y; acc16[10] += yv*w2.z; acc16[11] += yv*w2.w;
      acc16[12] += yv*w3.x; acc16[13] += yv*w3.y; acc16[14] += yv*w3.z; acc16[15] += yv*w3.w;
    }
  }
  float hOwn[16];
  #pragma unroll
  for (int t = 0; t < 16; ++t) hOwn[t] = tanh_fast(acc16[t]*s_s32);

  // ---- L5: g[32] = tanh(h @ Wm2); fold dot with Wm3; lane owns 8 ----
  #pragma unroll
  for (int q = 0; q < 8; ++q) acc8[q] = 0.f;
  #pragma unroll
  for (int s4 = 0; s4 < 4; ++s4){
    #pragma unroll
    for (int t = 0; t < 16; ++t){
      float hv = __shfl(hOwn[t], base + s4);
      const int j = s4*16 + t;
      const float4 w0 = *(const float4*)&Wm2[j*32 + k8];
      const float4 w1 = *(const float4*)&Wm2[j*32 + k8 + 4];
      acc8[0] += hv*w0.x; acc8[1] += hv*w0.y; acc8[2] += hv*w0.z; acc8[3] += hv*w0.w;
      acc8[4] += hv*w1.x; acc8[5] += hv*w1.y; acc8[6] += hv*w1.z; acc8[7] += hv*w1.w;
    }
  }
  float acc = 0.f;
  #pragma unroll
  for (int q = 0; q < 8; ++q) acc += tanh_fast(acc8[q]*s_s64) * Wm3[k8 + q];
  acc += __shfl_xor(acc, 1);
  acc += __shfl_xor(acc, 2);
  if (sub == 0) out[n] = acc * s_s32;
}

extern "C" void kernel_launch(void* const* d_in, const int* in_sizes, int n_in,
                              void* d_out, int out_size, void* d_ws, size_t ws_size,
                              hipStream_t stream) {
  const float* coords   = (const float*)d_in[0];
  const int*   species  = (const int*)  d_in[1];
  const int*   ei       = (const int*)  d_in[2];
  const float* Wna      = (const float*)d_in[4];
  const float* Wlin1    = (const float*)d_in[5];
  const float* Wr1      = (const float*)d_in[6];
  const float* Wr2      = (const float*)d_in[7];
  const float* Wr3      = (const float*)d_in[8];
  const float* W2s      = (const float*)d_in[9];
  const float* Wsc      = (const float*)d_in[11];
  const float* Wfin     = (const float*)d_in[12];
  const float* Wr       = (const float*)d_in[13];
  const float* Wm1      = (const float*)d_in[14];
  const float* Wm2      = (const float*)d_in[15];
  const float* Wm3      = (const float*)d_in[16];
  float* out = (float*)d_out;

  const int N = in_sizes[1];
  const int E = in_sizes[2] / 2;

  char* ws = (char*)d_ws;
  size_t offX1  = 0;                                 // x1tab 512B
  size_t offSC  = offX1 + 512;                       // sctab 1024B
  size_t offTAB = offSC + 1024;                      // tab (NTAB+2)*128 f32 (~2.1MB)
  size_t offH   = offTAB + (size_t)(NTAB+2)*128*4;   // hist [N] int
  size_t offP   = offH + (size_t)N*4;                // pay  [N*DEGCAP] u32 (~19.2MB)

  float*    x1tab = (float*)(ws + offX1);
  float*    sctab = (float*)(ws + offSC);
  float*    tab   = (float*)(ws + offTAB);
  int*      hist  = (int*)  (ws + offH);
  unsigned* pay   = (unsigned*)(ws + offP);

  hipMemsetAsync(hist, 0, (size_t)N*4, stream);

  k_pre<<<1, 256, 0, stream>>>(Wna, Wlin1, Wsc, x1tab, sctab);
  k_tab<<<(NTAB + 256) / 256, 256, 0, stream>>>(Wr1, Wr2, Wr3, x1tab, tab);
  k_edges<<<(E + 255) / 256, 256, 0, stream>>>(coords, ei, species, hist, pay, E);
  k_gather_node<<<((size_t)N*4 + 255) / 256, 256, 0, stream>>>(
      hist, pay, tab, sctab, species, W2s, Wfin, Wr, Wm1, Wm2, Wm3, out, N);
}

// Round 7
// 263.039 us; speedup vs baseline: 6.2434x; 1.0991x over previous
//
#include <hip/hip_runtime.h>
#include <math.h>

#define RMAX 4.0f
#define NTAB 4096    // intervals over [0,4); rows 0..4096 built (+pad)
#define DEGCAP 48    // max live in-degree bucket capacity (P(exceed) ~ 1e-11)

__device__ __forceinline__ float tanh_fast(float x){
  float e = __expf(2.0f * x);
  return 1.0f - 2.0f / (e + 1.0f);
}
__device__ __forceinline__ float normact(float s){
  float ns = fabsf(s);
  return s * tanh_fast(ns) / (ns + 1e-8f);
}

// ---------------- precompute per-species tables ----------------
__global__ void k_pre(const float* __restrict__ Wna, const float* __restrict__ Wlin1,
                      const float* __restrict__ Wsc,
                      float* __restrict__ x1tab, float* __restrict__ sctab){
  int id = threadIdx.x;
  if (id < 128){
    int c = id >> 5, j = id & 31;
    float acc = 0.f;
    for (int i = 0; i < 32; ++i) acc += Wna[c*32+i] * Wlin1[i*32+j];
    x1tab[id] = acc * (0.5f * 0.17677669529663687f);
  }
  if (id < 256){
    int c = id >> 6, k = id & 63;
    float acc = 0.f;
    for (int i = 0; i < 32; ++i) acc += Wna[c*32+i] * Wsc[(i*4+c)*64+k];
    sctab[id] = acc * (0.5f * 0.08838834764831843f);
  }
}

// ---------------- build radial table: tab[(i*4+c)*32+g] = w(r_i)[g]*x1tab[c][g] ----
__global__ void __launch_bounds__(256) k_tab(
    const float* __restrict__ Wr1, const float* __restrict__ Wr2,
    const float* __restrict__ Wr3, const float* __restrict__ x1tab,
    float* __restrict__ tab){
  __shared__ float sW1[8*64];
  __shared__ float sW2T[64*64];
  __shared__ float sW3[64*32];
  __shared__ float sX1[4*32];
  int t = threadIdx.x;
  for (int i = t; i < 512; i += 256) sW1[i] = Wr1[i] * 0.3535533905932738f;
  for (int i = t; i < 4096; i += 256){ int rr = i >> 6, cc = i & 63; sW2T[cc*64+rr] = Wr2[i] * 0.125f; }
  for (int i = t; i < 2048; i += 256){ int rr = i >> 5, cc = i & 31; sW3[i] = Wr3[rr*64+cc] * 0.125f; }
  for (int i = t; i < 128; i += 256) sX1[i] = x1tab[i];
  __syncthreads();
  int i = blockIdx.x * 256 + t;
  if (i > NTAB) return;
  float r = fmaxf((float)i * (RMAX / (float)NTAB), 1e-6f);

  float u = r * 0.25f;
  float u2 = u*u, u4 = u2*u2, u6 = u4*u2;
  float fc = 1.0f + u6 * (-28.0f + u * (48.0f - 21.0f * u));
  float pref = 0.5f / r * fc;
  float ea[8];
  #pragma unroll
  for (int k = 1; k <= 8; ++k) ea[k-1] = __sinf(0.78539816339744831f * r * (float)k) * pref;

  float h1[64];
  #pragma unroll
  for (int j = 0; j < 64; j += 4){
    float ax = 0.f, ay = 0.f, az = 0.f, aw = 0.f;
    #pragma unroll
    for (int k = 0; k < 8; ++k){
      const float4 w4 = *(const float4*)&sW1[k*64 + j];
      ax += ea[k]*w4.x; ay += ea[k]*w4.y; az += ea[k]*w4.z; aw += ea[k]*w4.w;
    }
    h1[j]   = tanh_fast(ax); h1[j+1] = tanh_fast(ay);
    h1[j+2] = tanh_fast(az); h1[j+3] = tanh_fast(aw);
  }

  float wsx[8], wsy[8], wsz[8], wsw[8];
  #pragma unroll
  for (int g = 0; g < 8; ++g){ wsx[g]=0.f; wsy[g]=0.f; wsz[g]=0.f; wsw[g]=0.f; }
  for (int j = 0; j < 64; ++j){
    float ax = 0.f, ay = 0.f, az = 0.f, aw = 0.f;
    #pragma unroll
    for (int k = 0; k < 64; k += 4){
      const float4 w4 = *(const float4*)&sW2T[j*64 + k];
      ax += h1[k]*w4.x; ay += h1[k+1]*w4.y; az += h1[k+2]*w4.z; aw += h1[k+3]*w4.w;
    }
    float tj = tanh_fast(ax + ay + az + aw);
    #pragma unroll
    for (int g = 0; g < 8; ++g){
      const float4 w4 = *(const float4*)&sW3[j*32 + g*4];
      wsx[g] += tj*w4.x; wsy[g] += tj*w4.y; wsz[g] += tj*w4.z; wsw[g] += tj*w4.w;
    }
  }

  #pragma unroll
  for (int c = 0; c < 4; ++c){
    float* row = tab + ((size_t)i*4 + c)*32;
    #pragma unroll
    for (int g = 0; g < 8; ++g){
      const float4 xv = *(const float4*)&sX1[c*32 + g*4];
      row[g*4+0] = wsx[g]*xv.x;
      row[g*4+1] = wsy[g]*xv.y;
      row[g*4+2] = wsz[g]*xv.z;
      row[g*4+3] = wsw[g]*xv.w;
    }
  }
}

// ---------------- single-pass bucketed edge build ----------------
// pay[d*DEGCAP + slot] = r packed with species(src) in low 2 bits
__global__ void __launch_bounds__(256) k_edges(
    const float* __restrict__ coords, const int* __restrict__ ei,
    const int* __restrict__ species, int* __restrict__ hist,
    unsigned* __restrict__ pay, int E){
  int i = blockIdx.x * blockDim.x + threadIdx.x;
  if (i >= E) return;
  int s = ei[i], d = ei[E + i];
  float3 cs = *(const float3*)(coords + 3*s);
  float3 cd = *(const float3*)(coords + 3*d);
  float dx = cd.x - cs.x, dy = cd.y - cs.y, dz = cd.z - cs.z;
  float r2 = dx*dx + dy*dy + dz*dz + 1e-8f;
  if (r2 >= RMAX*RMAX) return;           // fcut=0 -> msg exactly 0
  float r = sqrtf(r2);
  unsigned u = (__float_as_uint(r) & ~3u) | (unsigned)species[s];
  int pos = atomicAdd(&hist[d], 1);
  if (pos < DEGCAP) pay[(size_t)d * DEGCAP + pos] = u;
}

// ---------------- fused gather + node tail: 4 lanes per node ----------------
// Fully distributed state: lane `sub` only ever holds component slice
// [8*sub,8*sub+8) / [16*sub,16*sub+16) of every intermediate vector.
// Gather is TRANSPOSED (lane sums its 8 components over ALL edges) so the
// full a[32] never exists per-lane (round-6 post-mortem: redundant a[32]
// + wide accumulators -> 136 VGPR -> 3 waves/SIMD -> latency-bound).
__global__ void __launch_bounds__(256, 4) k_gather_node(
    const int* __restrict__ hist, const unsigned* __restrict__ pay,
    const float* __restrict__ tab, const float* __restrict__ sctab,
    const int* __restrict__ species,
    const float* __restrict__ W2s, const float* __restrict__ Wfin,
    const float* __restrict__ Wr,  const float* __restrict__ Wm1,
    const float* __restrict__ Wm2, const float* __restrict__ Wm3,
    float* __restrict__ out, int N){
  const float s_16s32 = 0.0625f * 0.17677669529663687f;
  const float s_s64   = 0.125f;
  const float s_s32   = 0.17677669529663687f;
  int gid = blockIdx.x * 256 + threadIdx.x;
  int n = gid >> 2;
  if (n >= N) return;
  int sub  = gid & 3;
  int base = (threadIdx.x & 63) & ~3;   // lane of sub==0 in this 4-lane group
  int k8  = sub * 8;
  int k16 = sub * 16;

  // ---- transposed gather: lane sums components [k8,k8+8) over ALL edges ----
  float aOwn[8];
  #pragma unroll
  for (int j = 0; j < 8; ++j) aOwn[j] = 0.f;
  int count = min(hist[n], DEGCAP);
  const unsigned* prow = pay + (size_t)n * DEGCAP;
  for (int e = 0; e < count; ++e){
    unsigned u = prow[e];
    int cc = (int)(u & 3u);
    float r = __uint_as_float(u & ~3u);
    float tt = r * ((float)NTAB / RMAX);
    int i0 = min((int)tt, NTAB - 1);
    float f = tt - (float)i0;
    const float4* r0 = (const float4*)(tab + ((size_t)i0*4 + cc)*32) + sub*2;
    const float4* r1 = r0 + 32;          // next r row (+4*32 floats)
    float4 p0 = r0[0], p1 = r0[1], q0 = r1[0], q1 = r1[1];
    aOwn[0] += p0.x + f*(q0.x - p0.x);
    aOwn[1] += p0.y + f*(q0.y - p0.y);
    aOwn[2] += p0.z + f*(q0.z - p0.z);
    aOwn[3] += p0.w + f*(q0.w - p0.w);
    aOwn[4] += p1.x + f*(q1.x - p1.x);
    aOwn[5] += p1.y + f*(q1.y - p1.y);
    aOwn[6] += p1.z + f*(q1.z - p1.z);
    aOwn[7] += p1.w + f*(q1.w - p1.w);
  }

  int c = species[n];

  // ---- L1: S[64]; lane owns [k16,k16+16); stream aOwn via shfl ----
  float acc16[16];
  #pragma unroll
  for (int t = 0; t < 16; ++t) acc16[t] = 0.f;
  #pragma unroll
  for (int s4 = 0; s4 < 4; ++s4){
    #pragma unroll
    for (int t = 0; t < 8; ++t){
      float av = __shfl(aOwn[t], base + s4);
      const int j = s4*8 + t;
      const float4 w0 = *(const float4*)&W2s[j*64 + k16];
      const float4 w1 = *(const float4*)&W2s[j*64 + k16 + 4];
      const float4 w2 = *(const float4*)&W2s[j*64 + k16 + 8];
      const float4 w3 = *(const float4*)&W2s[j*64 + k16 + 12];
      acc16[0]  += av*w0.x; acc16[1]  += av*w0.y; acc16[2]  += av*w0.z; acc16[3]  += av*w0.w;
      acc16[4]  += av*w1.x; acc16[5]  += av*w1.y; acc16[6]  += av*w1.z; acc16[7]  += av*w1.w;
      acc16[8]  += av*w2.x; acc16[9]  += av*w2.y; acc16[10] += av*w2.z; acc16[11] += av*w2.w;
      acc16[12] += av*w3.x; acc16[13] += av*w3.y; acc16[14] += av*w3.z; acc16[15] += av*w3.w;
    }
  }
  float sOwn[16];
  #pragma unroll
  for (int q = 0; q < 4; ++q){
    const float4 b4 = *(const float4*)&sctab[c*64 + k16 + q*4];
    sOwn[q*4+0] = normact(acc16[q*4+0]*s_16s32 + b4.x);
    sOwn[q*4+1] = normact(acc16[q*4+1]*s_16s32 + b4.y);
    sOwn[q*4+2] = normact(acc16[q*4+2]*s_16s32 + b4.z);
    sOwn[q*4+3] = normact(acc16[q*4+3]*s_16s32 + b4.w);
  }

  // ---- L2: y[32] = normact(S @ Wfin); lane owns [k8,k8+8); stream sOwn ----
  float acc8[8];
  #pragma unroll
  for (int q = 0; q < 8; ++q) acc8[q] = 0.f;
  #pragma unroll
  for (int s4 = 0; s4 < 4; ++s4){
    #pragma unroll
    for (int t = 0; t < 16; ++t){
      float sval = __shfl(sOwn[t], base + s4);
      const int j = s4*16 + t;
      const float4 w0 = *(const float4*)&Wfin[j*32 + k8];
      const float4 w1 = *(const float4*)&Wfin[j*32 + k8 + 4];
      acc8[0] += sval*w0.x; acc8[1] += sval*w0.y; acc8[2] += sval*w0.z; acc8[3] += sval*w0.w;
      acc8[4] += sval*w1.x; acc8[5] += sval*w1.y; acc8[6] += sval*w1.z; acc8[7] += sval*w1.w;
    }
  }
  float yOwn[8];
  #pragma unroll
  for (int q = 0; q < 8; ++q) yOwn[q] = normact(acc8[q]*s_s64);

  // ---- L3: y2[32] = y + normact(y @ Wr); lane owns [k8,k8+8) ----
  #pragma unroll
  for (int q = 0; q < 8; ++q) acc8[q] = 0.f;
  #pragma unroll
  for (int s4 = 0; s4 < 4; ++s4){
    #pragma unroll
    for (int t = 0; t < 8; ++t){
      float yval = __shfl(yOwn[t], base + s4);
      const int j = s4*8 + t;
      const float4 w0 = *(const float4*)&Wr[j*32 + k8];
      const float4 w1 = *(const float4*)&Wr[j*32 + k8 + 4];
      acc8[0] += yval*w0.x; acc8[1] += yval*w0.y; acc8[2] += yval*w0.z; acc8[3] += yval*w0.w;
      acc8[4] += yval*w1.x; acc8[5] += yval*w1.y; acc8[6] += yval*w1.z; acc8[7] += yval*w1.w;
    }
  }
  float y2Own[8];
  #pragma unroll
  for (int q = 0; q < 8; ++q) y2Own[q] = yOwn[q] + normact(acc8[q]*s_s32);

  // ---- L4: h[64] = tanh(y2 @ Wm1); lane owns [k16,k16+16) ----
  #pragma unroll
  for (int t = 0; t < 16; ++t) acc16[t] = 0.f;
  #pragma unroll
  for (int s4 = 0; s4 < 4; ++s4){
    #pragma unroll
    for (int t = 0; t < 8; ++t){
      float yv = __shfl(y2Own[t], base + s4);
      const int j = s4*8 + t;
      const float4 w0 = *(const float4*)&Wm1[j*64 + k16];
      const float4 w1 = *(const float4*)&Wm1[j*64 + k16 + 4];
      const float4 w2 = *(const float4*)&Wm1[j*64 + k16 + 8];
      const float4 w3 = *(const float4*)&Wm1[j*64 + k16 + 12];
      acc16[0]  += yv*w0.x; acc16[1]  += yv*w0.y; acc16[2]  += yv*w0.z; acc16[3]  += yv*w0.w;
      acc16[4]  += yv*w1.x; acc16[5]  += yv*w1.y; acc16[6]  += yv*w1.z; acc16[7]  += yv*w1.w;
      acc16[8]  += yv*w2.x; acc16[9]  += yv*w2.y; acc16[10] += yv*w2.z; acc16[11] += yv*w2.w;
      acc16[12] += yv*w3.x; acc16[13] += yv*w3.y; acc16[14] += yv*w3.z; acc16[15] += yv*w3.w;
    }
  }
  float hOwn[16];
  #pragma unroll
  for (int t = 0; t < 16; ++t) hOwn[t] = tanh_fast(acc16[t]*s_s32);

  // ---- L5: g[32] = tanh(h @ Wm2); fold dot with Wm3; lane owns [k8,k8+8) ----
  #pragma unroll
  for (int q = 0; q < 8; ++q) acc8[q] = 0.f;
  #pragma unroll
  for (int s4 = 0; s4 < 4; ++s4){
    #pragma unroll
    for (int t = 0; t < 16; ++t){
      float hv = __shfl(hOwn[t], base + s4);
      const int j = s4*16 + t;
      const float4 w0 = *(const float4*)&Wm2[j*32 + k8];
      const float4 w1 = *(const float4*)&Wm2[j*32 + k8 + 4];
      acc8[0] += hv*w0.x; acc8[1] += hv*w0.y; acc8[2] += hv*w0.z; acc8[3] += hv*w0.w;
      acc8[4] += hv*w1.x; acc8[5] += hv*w1.y; acc8[6] += hv*w1.z; acc8[7] += hv*w1.w;
    }
  }
  float acc = 0.f;
  #pragma unroll
  for (int q = 0; q < 8; ++q) acc += tanh_fast(acc8[q]*s_s64) * Wm3[k8 + q];
  acc += __shfl_xor(acc, 1);
  acc += __shfl_xor(acc, 2);
  if (sub == 0) out[n] = acc * s_s32;
}

extern "C" void kernel_launch(void* const* d_in, const int* in_sizes, int n_in,
                              void* d_out, int out_size, void* d_ws, size_t ws_size,
                              hipStream_t stream) {
  const float* coords   = (const float*)d_in[0];
  const int*   species  = (const int*)  d_in[1];
  const int*   ei       = (const int*)  d_in[2];
  const float* Wna      = (const float*)d_in[4];
  const float* Wlin1    = (const float*)d_in[5];
  const float* Wr1      = (const float*)d_in[6];
  const float* Wr2      = (const float*)d_in[7];
  const float* Wr3      = (const float*)d_in[8];
  const float* W2s      = (const float*)d_in[9];
  const float* Wsc      = (const float*)d_in[11];
  const float* Wfin     = (const float*)d_in[12];
  const float* Wr       = (const float*)d_in[13];
  const float* Wm1      = (const float*)d_in[14];
  const float* Wm2      = (const float*)d_in[15];
  const float* Wm3      = (const float*)d_in[16];
  float* out = (float*)d_out;

  const int N = in_sizes[1];
  const int E = in_sizes[2] / 2;

  char* ws = (char*)d_ws;
  size_t offX1  = 0;                                 // x1tab 512B
  size_t offSC  = offX1 + 512;                       // sctab 1024B
  size_t offTAB = offSC + 1024;                      // tab (NTAB+2)*128 f32 (~2.1MB)
  size_t offH   = offTAB + (size_t)(NTAB+2)*128*4;   // hist [N] int
  size_t offP   = offH + (size_t)N*4;                // pay  [N*DEGCAP] u32 (~19.2MB)

  float*    x1tab = (float*)(ws + offX1);
  float*    sctab = (float*)(ws + offSC);
  float*    tab   = (float*)(ws + offTAB);
  int*      hist  = (int*)  (ws + offH);
  unsigned* pay   = (unsigned*)(ws + offP);

  hipMemsetAsync(hist, 0, (size_t)N*4, stream);

  k_pre<<<1, 256, 0, stream>>>(Wna, Wlin1, Wsc, x1tab, sctab);
  k_tab<<<(NTAB + 256) / 256, 256, 0, stream>>>(Wr1, Wr2, Wr3, x1tab, tab);
  k_edges<<<(E + 255) / 256, 256, 0, stream>>>(coords, ei, species, hist, pay, E);
  k_gather_node<<<((size_t)N*4 + 255) / 256, 256, 0, stream>>>(
      hist, pay, tab, sctab, species, W2s, Wfin, Wr, Wm1, Wm2, Wm3, out, N);
}

// Round 9
// 214.962 us; speedup vs baseline: 7.6397x; 1.2237x over previous
//
#include <hip/hip_runtime.h>
#include <math.h>

#define RMAX 4.0f
#define NTAB 4096    // intervals over [0,4); rows 0..4096 built (+pad)
#define DEGCAP 48    // max live in-degree bucket capacity (P(exceed) ~ 1e-11)

__device__ __forceinline__ float tanh_fast(float x){
  float e = __expf(2.0f * x);
  return 1.0f - 2.0f / (e + 1.0f);
}
__device__ __forceinline__ float normact(float s){
  float ns = fabsf(s);
  return s * tanh_fast(ns) / (ns + 1e-8f);
}

// ---------------- precompute per-species tables ----------------
__global__ void k_pre(const float* __restrict__ Wna, const float* __restrict__ Wlin1,
                      const float* __restrict__ Wsc,
                      float* __restrict__ x1tab, float* __restrict__ sctab){
  int id = threadIdx.x;
  if (id < 128){
    int c = id >> 5, j = id & 31;
    float acc = 0.f;
    for (int i = 0; i < 32; ++i) acc += Wna[c*32+i] * Wlin1[i*32+j];
    x1tab[id] = acc * (0.5f * 0.17677669529663687f);
  }
  if (id < 256){
    int c = id >> 6, k = id & 63;
    float acc = 0.f;
    for (int i = 0; i < 32; ++i) acc += Wna[c*32+i] * Wsc[(i*4+c)*64+k];
    sctab[id] = acc * (0.5f * 0.08838834764831843f);
  }
}

// ---------------- build radial table: tab[(i*4+c)*32+g] = w(r_i)[g]*x1tab[c][g] ----
__global__ void __launch_bounds__(256) k_tab(
    const float* __restrict__ Wr1, const float* __restrict__ Wr2,
    const float* __restrict__ Wr3, const float* __restrict__ x1tab,
    float* __restrict__ tab){
  __shared__ float sW1[8*64];
  __shared__ float sW2T[64*64];
  __shared__ float sW3[64*32];
  __shared__ float sX1[4*32];
  int t = threadIdx.x;
  for (int i = t; i < 512; i += 256) sW1[i] = Wr1[i] * 0.3535533905932738f;
  for (int i = t; i < 4096; i += 256){ int rr = i >> 6, cc = i & 63; sW2T[cc*64+rr] = Wr2[i] * 0.125f; }
  for (int i = t; i < 2048; i += 256){ int rr = i >> 5, cc = i & 31; sW3[i] = Wr3[rr*64+cc] * 0.125f; }
  for (int i = t; i < 128; i += 256) sX1[i] = x1tab[i];
  __syncthreads();
  int i = blockIdx.x * 256 + t;
  if (i > NTAB) return;
  float r = fmaxf((float)i * (RMAX / (float)NTAB), 1e-6f);

  float u = r * 0.25f;
  float u2 = u*u, u4 = u2*u2, u6 = u4*u2;
  float fc = 1.0f + u6 * (-28.0f + u * (48.0f - 21.0f * u));
  float pref = 0.5f / r * fc;
  float ea[8];
  #pragma unroll
  for (int k = 1; k <= 8; ++k) ea[k-1] = __sinf(0.78539816339744831f * r * (float)k) * pref;

  float h1[64];
  #pragma unroll
  for (int j = 0; j < 64; j += 4){
    float ax = 0.f, ay = 0.f, az = 0.f, aw = 0.f;
    #pragma unroll
    for (int k = 0; k < 8; ++k){
      const float4 w4 = *(const float4*)&sW1[k*64 + j];
      ax += ea[k]*w4.x; ay += ea[k]*w4.y; az += ea[k]*w4.z; aw += ea[k]*w4.w;
    }
    h1[j]   = tanh_fast(ax); h1[j+1] = tanh_fast(ay);
    h1[j+2] = tanh_fast(az); h1[j+3] = tanh_fast(aw);
  }

  float wsx[8], wsy[8], wsz[8], wsw[8];
  #pragma unroll
  for (int g = 0; g < 8; ++g){ wsx[g]=0.f; wsy[g]=0.f; wsz[g]=0.f; wsw[g]=0.f; }
  for (int j = 0; j < 64; ++j){
    float ax = 0.f, ay = 0.f, az = 0.f, aw = 0.f;
    #pragma unroll
    for (int k = 0; k < 64; k += 4){
      const float4 w4 = *(const float4*)&sW2T[j*64 + k];
      ax += h1[k]*w4.x; ay += h1[k+1]*w4.y; az += h1[k+2]*w4.z; aw += h1[k+3]*w4.w;
    }
    float tj = tanh_fast(ax + ay + az + aw);
    #pragma unroll
    for (int g = 0; g < 8; ++g){
      const float4 w4 = *(const float4*)&sW3[j*32 + g*4];
      wsx[g] += tj*w4.x; wsy[g] += tj*w4.y; wsz[g] += tj*w4.z; wsw[g] += tj*w4.w;
    }
  }

  #pragma unroll
  for (int c = 0; c < 4; ++c){
    float* row = tab + ((size_t)i*4 + c)*32;
    #pragma unroll
    for (int g = 0; g < 8; ++g){
      const float4 xv = *(const float4*)&sX1[c*32 + g*4];
      row[g*4+0] = wsx[g]*xv.x;
      row[g*4+1] = wsy[g]*xv.y;
      row[g*4+2] = wsz[g]*xv.z;
      row[g*4+3] = wsw[g]*xv.w;
    }
  }
}

// ---------------- single-pass bucketed edge build ----------------
// pay[d*DEGCAP + slot] = r packed with species(src) in low 2 bits
__global__ void __launch_bounds__(256) k_edges(
    const float* __restrict__ coords, const int* __restrict__ ei,
    const int* __restrict__ species, int* __restrict__ hist,
    unsigned* __restrict__ pay, int E){
  int i = blockIdx.x * blockDim.x + threadIdx.x;
  if (i >= E) return;
  int s = ei[i], d = ei[E + i];
  float3 cs = *(const float3*)(coords + 3*s);
  float3 cd = *(const float3*)(coords + 3*d);
  float dx = cd.x - cs.x, dy = cd.y - cs.y, dz = cd.z - cs.z;
  float r2 = dx*dx + dy*dy + dz*dz + 1e-8f;
  if (r2 >= RMAX*RMAX) return;           // fcut=0 -> msg exactly 0
  float r = sqrtf(r2);
  unsigned u = (__float_as_uint(r) & ~3u) | (unsigned)species[s];
  int pos = atomicAdd(&hist[d], 1);
  if (pos < DEGCAP) pay[(size_t)d * DEGCAP + pos] = u;
}

// ---------------- fused gather + node tail: 8 lanes per node ----------------
// Round-7 post-mortem: 4-lane version was TLP-starved (6.1 waves/SIMD
// theoretical, 2.7 measured, VALUBusy 23%). 8 lanes/node doubles wave count
// (12.2/SIMD available -> residency pegs at the 8/SIMD cap) and halves
// per-lane work. Lane `sub` owns slice [4*sub,4*sub+4) of 32-vecs and
// [8*sub,8*sub+8) of 64-vecs; cross-lane values stream via __shfl inside
// the dot loops (never materialized -> no spills).
__global__ void __launch_bounds__(256, 8) k_gather_node(
    const int* __restrict__ hist, const unsigned* __restrict__ pay,
    const float* __restrict__ tab, const float* __restrict__ sctab,
    const int* __restrict__ species,
    const float* __restrict__ W2s, const float* __restrict__ Wfin,
    const float* __restrict__ Wr,  const float* __restrict__ Wm1,
    const float* __restrict__ Wm2, const float* __restrict__ Wm3,
    float* __restrict__ out, int N){
  const float s_16s32 = 0.0625f * 0.17677669529663687f;
  const float s_s64   = 0.125f;
  const float s_s32   = 0.17677669529663687f;
  int gid = blockIdx.x * 256 + threadIdx.x;
  int n = gid >> 3;
  if (n >= N) return;
  int sub  = gid & 7;
  int base = (threadIdx.x & 63) & ~7;   // lane of sub==0 in this 8-lane group
  int k4 = sub * 4;
  int k8 = sub * 8;

  // ---- transposed gather: lane sums components [k4,k4+4) over ALL edges ----
  float aOwn[4];
  #pragma unroll
  for (int j = 0; j < 4; ++j) aOwn[j] = 0.f;
  int count = min(hist[n], DEGCAP);
  const unsigned* prow = pay + (size_t)n * DEGCAP;
  for (int e = 0; e < count; ++e){
    unsigned u = prow[e];
    int cc = (int)(u & 3u);
    float r = __uint_as_float(u & ~3u);
    float tt = r * ((float)NTAB / RMAX);
    int i0 = min((int)tt, NTAB - 1);
    float f = tt - (float)i0;
    const float4* r0 = (const float4*)(tab + ((size_t)i0*4 + cc)*32) + sub;
    const float4* r1 = r0 + 32;          // next r row (+4*32 floats)
    float4 p = r0[0], q = r1[0];
    aOwn[0] += p.x + f*(q.x - p.x);
    aOwn[1] += p.y + f*(q.y - p.y);
    aOwn[2] += p.z + f*(q.z - p.z);
    aOwn[3] += p.w + f*(q.w - p.w);
  }

  int c = species[n];

  // ---- L1: S[64]; lane owns [k8,k8+8); stream aOwn via shfl ----
  float acc8[8];
  #pragma unroll
  for (int t = 0; t < 8; ++t) acc8[t] = 0.f;
  #pragma unroll
  for (int s8 = 0; s8 < 8; ++s8){
    #pragma unroll
    for (int t = 0; t < 4; ++t){
      float av = __shfl(aOwn[t], base + s8);
      const int j = s8*4 + t;
      const float4 w0 = *(const float4*)&W2s[j*64 + k8];
      const float4 w1 = *(const float4*)&W2s[j*64 + k8 + 4];
      acc8[0] += av*w0.x; acc8[1] += av*w0.y; acc8[2] += av*w0.z; acc8[3] += av*w0.w;
      acc8[4] += av*w1.x; acc8[5] += av*w1.y; acc8[6] += av*w1.z; acc8[7] += av*w1.w;
    }
  }
  float sOwn[8];
  {
    const float4 b0 = *(const float4*)&sctab[c*64 + k8];
    const float4 b1 = *(const float4*)&sctab[c*64 + k8 + 4];
    sOwn[0] = normact(acc8[0]*s_16s32 + b0.x);
    sOwn[1] = normact(acc8[1]*s_16s32 + b0.y);
    sOwn[2] = normact(acc8[2]*s_16s32 + b0.z);
    sOwn[3] = normact(acc8[3]*s_16s32 + b0.w);
    sOwn[4] = normact(acc8[4]*s_16s32 + b1.x);
    sOwn[5] = normact(acc8[5]*s_16s32 + b1.y);
    sOwn[6] = normact(acc8[6]*s_16s32 + b1.z);
    sOwn[7] = normact(acc8[7]*s_16s32 + b1.w);
  }

  // ---- L2: y[32] = normact(S @ Wfin); lane owns [k4,k4+4); stream sOwn ----
  float acc4[4];
  #pragma unroll
  for (int q = 0; q < 4; ++q) acc4[q] = 0.f;
  #pragma unroll
  for (int s8 = 0; s8 < 8; ++s8){
    #pragma unroll
    for (int t = 0; t < 8; ++t){
      float sval = __shfl(sOwn[t], base + s8);
      const int j = s8*8 + t;
      const float4 w = *(const float4*)&Wfin[j*32 + k4];
      acc4[0] += sval*w.x; acc4[1] += sval*w.y; acc4[2] += sval*w.z; acc4[3] += sval*w.w;
    }
  }
  float yOwn[4];
  #pragma unroll
  for (int q = 0; q < 4; ++q) yOwn[q] = normact(acc4[q]*s_s64);

  // ---- L3: y2[32] = y + normact(y @ Wr); lane owns [k4,k4+4) ----
  #pragma unroll
  for (int q = 0; q < 4; ++q) acc4[q] = 0.f;
  #pragma unroll
  for (int s8 = 0; s8 < 8; ++s8){
    #pragma unroll
    for (int t = 0; t < 4; ++t){
      float yval = __shfl(yOwn[t], base + s8);
      const int j = s8*4 + t;
      const float4 w = *(const float4*)&Wr[j*32 + k4];
      acc4[0] += yval*w.x; acc4[1] += yval*w.y; acc4[2] += yval*w.z; acc4[3] += yval*w.w;
    }
  }
  float y2Own[4];
  #pragma unroll
  for (int q = 0; q < 4; ++q) y2Own[q] = yOwn[q] + normact(acc4[q]*s_s32);

  // ---- L4: h[64] = tanh(y2 @ Wm1); lane owns [k8,k8+8) ----
  #pragma unroll
  for (int t = 0; t < 8; ++t) acc8[t] = 0.f;
  #pragma unroll
  for (int s8 = 0; s8 < 8; ++s8){
    #pragma unroll
    for (int t = 0; t < 4; ++t){
      float yv = __shfl(y2Own[t], base + s8);
      const int j = s8*4 + t;
      const float4 w0 = *(const float4*)&Wm1[j*64 + k8];
      const float4 w1 = *(const float4*)&Wm1[j*64 + k8 + 4];
      acc8[0] += yv*w0.x; acc8[1] += yv*w0.y; acc8[2] += yv*w0.z; acc8[3] += yv*w0.w;
      acc8[4] += yv*w1.x; acc8[5] += yv*w1.y; acc8[6] += yv*w1.z; acc8[7] += yv*w1.w;
    }
  }
  float hOwn[8];
  #pragma unroll
  for (int t = 0; t < 8; ++t) hOwn[t] = tanh_fast(acc8[t]*s_s32);

  // ---- L5: g[32] = tanh(h @ Wm2); fold dot with Wm3; lane owns [k4,k4+4) ----
  #pragma unroll
  for (int q = 0; q < 4; ++q) acc4[q] = 0.f;
  #pragma unroll
  for (int s8 = 0; s8 < 8; ++s8){
    #pragma unroll
    for (int t = 0; t < 8; ++t){
      float hv = __shfl(hOwn[t], base + s8);
      const int j = s8*8 + t;
      const float4 w = *(const float4*)&Wm2[j*32 + k4];
      acc4[0] += hv*w.x; acc4[1] += hv*w.y; acc4[2] += hv*w.z; acc4[3] += hv*w.w;
    }
  }
  float acc = 0.f;
  #pragma unroll
  for (int q = 0; q < 4; ++q) acc += tanh_fast(acc4[q]*s_s64) * Wm3[k4 + q];
  acc += __shfl_xor(acc, 1);
  acc += __shfl_xor(acc, 2);
  acc += __shfl_xor(acc, 4);
  if (sub == 0) out[n] = acc * s_s32;
}

extern "C" void kernel_launch(void* const* d_in, const int* in_sizes, int n_in,
                              void* d_out, int out_size, void* d_ws, size_t ws_size,
                              hipStream_t stream) {
  const float* coords   = (const float*)d_in[0];
  const int*   species  = (const int*)  d_in[1];
  const int*   ei       = (const int*)  d_in[2];
  const float* Wna      = (const float*)d_in[4];
  const float* Wlin1    = (const float*)d_in[5];
  const float* Wr1      = (const float*)d_in[6];
  const float* Wr2      = (const float*)d_in[7];
  const float* Wr3      = (const float*)d_in[8];
  const float* W2s      = (const float*)d_in[9];
  const float* Wsc      = (const float*)d_in[11];
  const float* Wfin     = (const float*)d_in[12];
  const float* Wr       = (const float*)d_in[13];
  const float* Wm1      = (const float*)d_in[14];
  const float* Wm2      = (const float*)d_in[15];
  const float* Wm3      = (const float*)d_in[16];
  float* out = (float*)d_out;

  const int N = in_sizes[1];
  const int E = in_sizes[2] / 2;

  char* ws = (char*)d_ws;
  size_t offX1  = 0;                                 // x1tab 512B
  size_t offSC  = offX1 + 512;                       // sctab 1024B
  size_t offTAB = offSC + 1024;                      // tab (NTAB+2)*128 f32 (~2.1MB)
  size_t offH   = offTAB + (size_t)(NTAB+2)*128*4;   // hist [N] int
  size_t offP   = offH + (size_t)N*4;                // pay  [N*DEGCAP] u32 (~19.2MB)

  float*    x1tab = (float*)(ws + offX1);
  float*    sctab = (float*)(ws + offSC);
  float*    tab   = (float*)(ws + offTAB);
  int*      hist  = (int*)  (ws + offH);
  unsigned* pay   = (unsigned*)(ws + offP);

  hipMemsetAsync(hist, 0, (size_t)N*4, stream);

  k_pre<<<1, 256, 0, stream>>>(Wna, Wlin1, Wsc, x1tab, sctab);
  k_tab<<<(NTAB + 256) / 256, 256, 0, stream>>>(Wr1, Wr2, Wr3, x1tab, tab);
  k_edges<<<(E + 255) / 256, 256, 0, stream>>>(coords, ei, species, hist, pay, E);
  k_gather_node<<<((size_t)N*8 + 255) / 256, 256, 0, stream>>>(
      hist, pay, tab, sctab, species, W2s, Wfin, Wr, Wm1, Wm2, Wm3, out, N);
}